// Round 1
// baseline (2527.776 us; speedup 1.0000x reference)
//
#include <hip/hip_runtime.h>
#include <cstddef>

#define TB   2
#define TT   2048
#define TC   768
#define NHD  12
#define HDD  64
#define QKVN 2304
#define BTM  4096   // TB*TT

// ws layout (float offsets); total 21,041,152 floats = 84.2 MB
#define FF_OFF   9437184ull    // BTM*QKVN
#define GSUM_OFF 17825792ull   // + TB*TT*TT
#define FSUM_OFF 17891328ull   // + TB*16*TT
#define YATT_OFF 17895424ull   // + TB*TT
#define YSZ      3145728       // BTM*TC

// ---------------------------------------------------------------- GEMM 128x128
// C[M,N] = A[M,K] @ W[K,N] + bias[N]; M,N multiples of 128, K multiple of 16.
__global__ __launch_bounds__(256) void gemm_f32_128(
    const float* __restrict__ A, const float* __restrict__ W,
    const float* __restrict__ bias, float* __restrict__ Co,
    int M, int N, int K)
{
    __shared__ __align__(16) float As[16][132];
    __shared__ __align__(16) float Bs[16][132];
    const int tid = threadIdx.x;
    const int tx = tid & 15, ty = tid >> 4;
    const int row0 = blockIdx.y * 128, col0 = blockIdx.x * 128;

    float acc[8][8];
#pragma unroll
    for (int i = 0; i < 8; ++i)
#pragma unroll
        for (int j = 0; j < 8; ++j) acc[i][j] = 0.f;

    for (int k0 = 0; k0 < K; k0 += 16) {
#pragma unroll
        for (int u = 0; u < 2; ++u) {
            int f4 = tid * 2 + u;
            int ra = f4 >> 2, ca = (f4 & 3) * 4;
            float4 av = *(const float4*)(A + (size_t)(row0 + ra) * K + k0 + ca);
            As[ca + 0][ra] = av.x; As[ca + 1][ra] = av.y;
            As[ca + 2][ra] = av.z; As[ca + 3][ra] = av.w;
            int rb = f4 >> 5, cb = (f4 & 31) * 4;
            float4 bv = *(const float4*)(W + (size_t)(k0 + rb) * N + col0 + cb);
            *(float4*)&Bs[rb][cb] = bv;
        }
        __syncthreads();
#pragma unroll
        for (int kk = 0; kk < 16; ++kk) {
            float4 t0 = *(const float4*)&As[kk][ty * 4];
            float4 t1 = *(const float4*)&As[kk][64 + ty * 4];
            float4 t2 = *(const float4*)&Bs[kk][tx * 4];
            float4 t3 = *(const float4*)&Bs[kk][64 + tx * 4];
            float a[8], bq[8];
            a[0]=t0.x; a[1]=t0.y; a[2]=t0.z; a[3]=t0.w;
            a[4]=t1.x; a[5]=t1.y; a[6]=t1.z; a[7]=t1.w;
            bq[0]=t2.x; bq[1]=t2.y; bq[2]=t2.z; bq[3]=t2.w;
            bq[4]=t3.x; bq[5]=t3.y; bq[6]=t3.z; bq[7]=t3.w;
#pragma unroll
            for (int i = 0; i < 8; ++i)
#pragma unroll
                for (int j = 0; j < 8; ++j)
                    acc[i][j] = fmaf(a[i], bq[j], acc[i][j]);
        }
        __syncthreads();
    }

    float4 bi0 = *(const float4*)(bias + col0 + tx * 4);
    float4 bi1 = *(const float4*)(bias + col0 + 64 + tx * 4);
#pragma unroll
    for (int ih = 0; ih < 2; ++ih)
#pragma unroll
        for (int i = 0; i < 4; ++i) {
            int r = row0 + ih * 64 + ty * 4 + i;
            int ai = ih * 4 + i;
            float4 c0, c1;
            c0.x = acc[ai][0] + bi0.x; c0.y = acc[ai][1] + bi0.y;
            c0.z = acc[ai][2] + bi0.z; c0.w = acc[ai][3] + bi0.w;
            c1.x = acc[ai][4] + bi1.x; c1.y = acc[ai][5] + bi1.y;
            c1.z = acc[ai][6] + bi1.z; c1.w = acc[ai][7] + bi1.w;
            *(float4*)(Co + (size_t)r * N + col0 + tx * 4) = c0;
            *(float4*)(Co + (size_t)r * N + col0 + 64 + tx * 4) = c1;
        }
}

// ------------------------------------------------- head-0 selection scores S
// S[b,t,s] = (0<s && s<t) ? max(q0[t].k0[s]/8, 0) : 0   (full matrix written)
__global__ __launch_bounds__(256) void s_head0_kernel(
    const float* __restrict__ qkv, float* __restrict__ S)
{
    const int tid = threadIdx.x;
    const int tx = tid & 15, ty = tid >> 4;
    const int s0 = blockIdx.x * 64, t0 = blockIdx.y * 64, b = blockIdx.z;

    if (s0 > t0 + 63) {  // fully above diagonal: zero-fill
        float4 z = make_float4(0.f, 0.f, 0.f, 0.f);
#pragma unroll
        for (int i = 0; i < 4; ++i) {
            int t = t0 + ty * 4 + i;
            *(float4*)(S + ((size_t)b * TT + t) * TT + s0 + tx * 4) = z;
        }
        return;
    }

    __shared__ __align__(16) float As[16][68];
    __shared__ __align__(16) float Bs[16][68];
    float acc[4][4];
#pragma unroll
    for (int i = 0; i < 4; ++i)
#pragma unroll
        for (int j = 0; j < 4; ++j) acc[i][j] = 0.f;

    for (int k0 = 0; k0 < 64; k0 += 16) {
        int r = tid >> 2, c = (tid & 3) * 4;
        float4 av = *(const float4*)(qkv + ((size_t)b * TT + t0 + r) * QKVN + k0 + c);
        As[c + 0][r] = av.x; As[c + 1][r] = av.y;
        As[c + 2][r] = av.z; As[c + 3][r] = av.w;
        float4 bv = *(const float4*)(qkv + ((size_t)b * TT + s0 + r) * QKVN + 768 + k0 + c);
        Bs[c + 0][r] = bv.x; Bs[c + 1][r] = bv.y;
        Bs[c + 2][r] = bv.z; Bs[c + 3][r] = bv.w;
        __syncthreads();
#pragma unroll
        for (int kk = 0; kk < 16; ++kk) {
            float4 a4 = *(const float4*)&As[kk][ty * 4];
            float4 b4 = *(const float4*)&Bs[kk][tx * 4];
            float a[4] = {a4.x, a4.y, a4.z, a4.w};
            float bb[4] = {b4.x, b4.y, b4.z, b4.w};
#pragma unroll
            for (int i = 0; i < 4; ++i)
#pragma unroll
                for (int j = 0; j < 4; ++j)
                    acc[i][j] = fmaf(a[i], bb[j], acc[i][j]);
        }
        __syncthreads();
    }

#pragma unroll
    for (int i = 0; i < 4; ++i) {
        int t = t0 + ty * 4 + i;
        int sb = s0 + tx * 4;
        float4 o;
        o.x = (sb + 0 > 0 && sb + 0 < t) ? fmaxf(acc[i][0] * 0.125f, 0.f) : 0.f;
        o.y = (sb + 1 > 0 && sb + 1 < t) ? fmaxf(acc[i][1] * 0.125f, 0.f) : 0.f;
        o.z = (sb + 2 > 0 && sb + 2 < t) ? fmaxf(acc[i][2] * 0.125f, 0.f) : 0.f;
        o.w = (sb + 3 > 0 && sb + 3 < t) ? fmaxf(acc[i][3] * 0.125f, 0.f) : 0.f;
        *(float4*)(S + ((size_t)b * TT + t) * TT + sb) = o;
    }
}

// ---------------------------------------------- segmented exclusive scan (t)
// FF[b,t,s] = sum_{t'<t} S[b,t',s]; in place. 16 groups of 128 rows.
__global__ void scan_pass1(const float* __restrict__ S, float* __restrict__ gsum)
{
    int s = blockIdx.x * 256 + threadIdx.x;
    int g = blockIdx.y, b = blockIdx.z;
    const float* base = S + ((size_t)b * TT + g * 128) * TT + s;
    float acc = 0.f;
#pragma unroll 4
    for (int r = 0; r < 128; ++r) acc += base[(size_t)r * TT];
    gsum[((size_t)b * 16 + g) * TT + s] = acc;
}

__global__ void scan_pass2(float* __restrict__ gsum)
{
    int idx = blockIdx.x * 256 + threadIdx.x;  // 0..4095
    int b = idx >> 11, s = idx & 2047;
    float acc = 0.f;
#pragma unroll
    for (int g = 0; g < 16; ++g) {
        size_t a = ((size_t)b * 16 + g) * TT + s;
        float v = gsum[a];
        gsum[a] = acc;
        acc += v;
    }
}

__global__ void scan_pass3(float* __restrict__ S, const float* __restrict__ gsum)
{
    int s = blockIdx.x * 256 + threadIdx.x;
    int g = blockIdx.y, b = blockIdx.z;
    float acc = gsum[((size_t)b * 16 + g) * TT + s];
    float* base = S + ((size_t)b * TT + g * 128) * TT + s;
#pragma unroll 4
    for (int r = 0; r < 128; ++r) {
        float v = base[(size_t)r * TT];
        base[(size_t)r * TT] = acc;
        acc += v;
    }
}

// ------------------------------------------------- FF_sum[b,t] = sum clip(FF)
__global__ void ffsum_kernel(const float* __restrict__ FF, float* __restrict__ FS)
{
    int row = blockIdx.x;  // b*TT + t
    int tid = threadIdx.x;
    const float* p = FF + (size_t)row * TT;
    float acc = 0.f;
#pragma unroll
    for (int s = tid; s < TT; s += 256) {
        float v = p[s];
        acc += fminf(fmaxf(v, 0.f), 1.f);
    }
#pragma unroll
    for (int off = 32; off > 0; off >>= 1) acc += __shfl_down(acc, off, 64);
    __shared__ float red[4];
    if ((tid & 63) == 0) red[tid >> 6] = acc;
    __syncthreads();
    if (tid == 0) FS[row] = (red[0] + red[1]) + (red[2] + red[3]);
}

// ----------------------------------------------------- M[0,b,i,j] = i - FS[b,j]
__global__ void mout_kernel(const float* __restrict__ FS, float* __restrict__ Mo)
{
    size_t idx = (size_t)blockIdx.x * 256 + threadIdx.x;
    int j = (int)(idx & 2047);
    int i = (int)((idx >> 11) & 2047);
    int b = (int)(idx >> 22);
    Mo[idx] = (float)i - FS[b * TT + j];
}

// -------------------------------------------- flash attention with FF penalty
// one thread per query row t; 64-row blocks; K/V tiles of 16 in LDS.
__global__ __launch_bounds__(64) void attn_kernel(
    const float* __restrict__ qkv, const float* __restrict__ FF,
    float* __restrict__ Y)
{
    const int tt = (TT / 64 - 1) - blockIdx.x;  // heavy tiles first
    const int h = blockIdx.y, b = blockIdx.z;
    const int tid = threadIdx.x;
    const int t = tt * 64 + tid;

    float q[64];
    {
        const float* qp = qkv + ((size_t)(b * TT + t)) * QKVN + h * 64;
#pragma unroll
        for (int c = 0; c < 16; ++c) {
            float4 v = *(const float4*)(qp + c * 4);
            q[c * 4 + 0] = v.x; q[c * 4 + 1] = v.y;
            q[c * 4 + 2] = v.z; q[c * 4 + 3] = v.w;
        }
    }
    float o[64];
#pragma unroll
    for (int d = 0; d < 64; ++d) o[d] = 0.f;
    float mx = -3.0e38f, l = 0.f;

    __shared__ __align__(16) float4 Ks[16][16];
    __shared__ __align__(16) float4 Vs[16][16];
    const float* ffrow = FF + (size_t)(b * TT + t) * TT;
    const int ntiles = tt * 4 + 4;

#pragma unroll 1
    for (int it = 0; it < ntiles; ++it) {
        const int s0 = it * 16;
        __syncthreads();
#pragma unroll
        for (int u = 0; u < 4; ++u) {
            int f = u * 64 + tid;
            int r = f >> 4, c = f & 15;
            size_t base = ((size_t)(b * TT) + s0 + r) * QKVN + h * 64 + c * 4;
            Ks[r][c] = *(const float4*)(qkv + base + 768);
            Vs[r][c] = *(const float4*)(qkv + base + 1536);
        }
        __syncthreads();

        float ff[16];
#pragma unroll
        for (int u = 0; u < 4; ++u) {
            float4 f4 = *(const float4*)(ffrow + s0 + u * 4);
            ff[u * 4 + 0] = f4.x; ff[u * 4 + 1] = f4.y;
            ff[u * 4 + 2] = f4.z; ff[u * 4 + 3] = f4.w;
        }

        float sc[16];
        float mnew = mx;
#pragma unroll
        for (int j = 0; j < 16; ++j) {
            int s = s0 + j;
            float d0 = 0.f, d1 = 0.f, d2 = 0.f, d3 = 0.f;
#pragma unroll
            for (int c = 0; c < 16; ++c) {
                float4 kv = Ks[j][c];
                d0 = fmaf(q[c * 4 + 0], kv.x, d0);
                d1 = fmaf(q[c * 4 + 1], kv.y, d1);
                d2 = fmaf(q[c * 4 + 2], kv.z, d2);
                d3 = fmaf(q[c * 4 + 3], kv.w, d3);
            }
            float dot = (d0 + d1) + (d2 + d3);
            sc[j] = (s <= t) ? (dot * 0.125f - ff[j]) : -3.0e38f;
            mnew = fmaxf(mnew, sc[j]);
        }

        float scale = __expf(mx - mnew);
        l *= scale;
#pragma unroll
        for (int d = 0; d < 64; ++d) o[d] *= scale;
        mx = mnew;

#pragma unroll
        for (int j = 0; j < 16; ++j) {
            float p = __expf(sc[j] - mx);
            l += p;
#pragma unroll
            for (int c = 0; c < 16; ++c) {
                float4 vv = Vs[j][c];
                o[c * 4 + 0] = fmaf(p, vv.x, o[c * 4 + 0]);
                o[c * 4 + 1] = fmaf(p, vv.y, o[c * 4 + 1]);
                o[c * 4 + 2] = fmaf(p, vv.z, o[c * 4 + 2]);
                o[c * 4 + 3] = fmaf(p, vv.w, o[c * 4 + 3]);
            }
        }
    }

    const float inv = 1.0f / l;
    float* yo = Y + (size_t)(b * TT + t) * TC + h * 64;
#pragma unroll
    for (int c = 0; c < 16; ++c) {
        float4 v;
        v.x = o[c * 4 + 0] * inv; v.y = o[c * 4 + 1] * inv;
        v.z = o[c * 4 + 2] * inv; v.w = o[c * 4 + 3] * inv;
        *(float4*)(yo + c * 4) = v;
    }
}

// ---------------------------------------------------------------------- launch
extern "C" void kernel_launch(void* const* d_in, const int* in_sizes, int n_in,
                              void* d_out, int out_size, void* d_ws, size_t ws_size,
                              hipStream_t stream)
{
    const float* x      = (const float*)d_in[0];
    const float* W_attn = (const float*)d_in[1];
    const float* b_attn = (const float*)d_in[2];
    const float* W_proj = (const float*)d_in[3];
    const float* b_proj = (const float*)d_in[4];
    float* out = (float*)d_out;
    float* ws  = (float*)d_ws;

    float* qkv  = ws;                 // [4096, 2304]
    float* FFb  = ws + FF_OFF;        // [B, T, T]   S -> FF in place
    float* gsum = ws + GSUM_OFF;      // [B, 16, T]
    float* fsum = ws + FSUM_OFF;      // [B, T]
    float* yatt = ws + YATT_OFF;      // [4096, 768]

    gemm_f32_128<<<dim3(QKVN / 128, BTM / 128), dim3(256), 0, stream>>>(
        x, W_attn, b_attn, qkv, BTM, QKVN, TC);

    s_head0_kernel<<<dim3(TT / 64, TT / 64, TB), dim3(256), 0, stream>>>(qkv, FFb);

    scan_pass1<<<dim3(TT / 256, 16, TB), dim3(256), 0, stream>>>(FFb, gsum);
    scan_pass2<<<dim3(TB * TT / 256), dim3(256), 0, stream>>>(gsum);
    scan_pass3<<<dim3(TT / 256, 16, TB), dim3(256), 0, stream>>>(FFb, gsum);

    ffsum_kernel<<<dim3(TB * TT), dim3(256), 0, stream>>>(FFb, fsum);

    attn_kernel<<<dim3(TT / 64, NHD, TB), dim3(64), 0, stream>>>(qkv, FFb, yatt);

    gemm_f32_128<<<dim3(TC / 128, BTM / 128), dim3(256), 0, stream>>>(
        yatt, W_proj, b_proj, out, BTM, TC, TC);

    mout_kernel<<<dim3((unsigned)((size_t)TB * TT * TT / 256)), dim3(256), 0, stream>>>(
        fsum, out + YSZ);
}

// Round 2
// 1393.131 us; speedup vs baseline: 1.8145x; 1.8145x over previous
//
#include <hip/hip_runtime.h>
#include <cstddef>

#define TB   2
#define TT   2048
#define TC   768
#define NHD  12
#define HDD  64
#define QKVN 2304
#define BTM  4096   // TB*TT

// ws layout (float offsets); total 21,041,152 floats = 84.2 MB
#define FF_OFF   9437184ull    // BTM*QKVN
#define GSUM_OFF 17825792ull   // + TB*TT*TT
#define FSUM_OFF 17891328ull   // + TB*16*TT
#define YATT_OFF 17895424ull   // + TB*TT
#define YSZ      3145728       // BTM*TC

// ---------------------------------------------------------------- GEMM 128x128
// C[M,N] = A[M,K] @ W[K,N] + bias[N]; M,N multiples of 128, K multiple of 16.
__global__ __launch_bounds__(256) void gemm_f32_128(
    const float* __restrict__ A, const float* __restrict__ W,
    const float* __restrict__ bias, float* __restrict__ Co,
    int M, int N, int K)
{
    __shared__ __align__(16) float As[16][132];
    __shared__ __align__(16) float Bs[16][132];
    const int tid = threadIdx.x;
    const int tx = tid & 15, ty = tid >> 4;
    const int row0 = blockIdx.y * 128, col0 = blockIdx.x * 128;

    float acc[8][8];
#pragma unroll
    for (int i = 0; i < 8; ++i)
#pragma unroll
        for (int j = 0; j < 8; ++j) acc[i][j] = 0.f;

    for (int k0 = 0; k0 < K; k0 += 16) {
#pragma unroll
        for (int u = 0; u < 2; ++u) {
            int f4 = tid * 2 + u;
            int ra = f4 >> 2, ca = (f4 & 3) * 4;
            float4 av = *(const float4*)(A + (size_t)(row0 + ra) * K + k0 + ca);
            As[ca + 0][ra] = av.x; As[ca + 1][ra] = av.y;
            As[ca + 2][ra] = av.z; As[ca + 3][ra] = av.w;
            int rb = f4 >> 5, cb = (f4 & 31) * 4;
            float4 bv = *(const float4*)(W + (size_t)(k0 + rb) * N + col0 + cb);
            *(float4*)&Bs[rb][cb] = bv;
        }
        __syncthreads();
#pragma unroll
        for (int kk = 0; kk < 16; ++kk) {
            float4 t0 = *(const float4*)&As[kk][ty * 4];
            float4 t1 = *(const float4*)&As[kk][64 + ty * 4];
            float4 t2 = *(const float4*)&Bs[kk][tx * 4];
            float4 t3 = *(const float4*)&Bs[kk][64 + tx * 4];
            float a[8], bq[8];
            a[0]=t0.x; a[1]=t0.y; a[2]=t0.z; a[3]=t0.w;
            a[4]=t1.x; a[5]=t1.y; a[6]=t1.z; a[7]=t1.w;
            bq[0]=t2.x; bq[1]=t2.y; bq[2]=t2.z; bq[3]=t2.w;
            bq[4]=t3.x; bq[5]=t3.y; bq[6]=t3.z; bq[7]=t3.w;
#pragma unroll
            for (int i = 0; i < 8; ++i)
#pragma unroll
                for (int j = 0; j < 8; ++j)
                    acc[i][j] = fmaf(a[i], bq[j], acc[i][j]);
        }
        __syncthreads();
    }

    float4 bi0 = *(const float4*)(bias + col0 + tx * 4);
    float4 bi1 = *(const float4*)(bias + col0 + 64 + tx * 4);
#pragma unroll
    for (int ih = 0; ih < 2; ++ih)
#pragma unroll
        for (int i = 0; i < 4; ++i) {
            int r = row0 + ih * 64 + ty * 4 + i;
            int ai = ih * 4 + i;
            float4 c0, c1;
            c0.x = acc[ai][0] + bi0.x; c0.y = acc[ai][1] + bi0.y;
            c0.z = acc[ai][2] + bi0.z; c0.w = acc[ai][3] + bi0.w;
            c1.x = acc[ai][4] + bi1.x; c1.y = acc[ai][5] + bi1.y;
            c1.z = acc[ai][6] + bi1.z; c1.w = acc[ai][7] + bi1.w;
            *(float4*)(Co + (size_t)r * N + col0 + tx * 4) = c0;
            *(float4*)(Co + (size_t)r * N + col0 + 64 + tx * 4) = c1;
        }
}

// ------------------------------------------------- head-0 selection scores S
// S[b,t,s] = (0<s && s<t) ? max(q0[t].k0[s]/8, 0) : 0   (full matrix written)
__global__ __launch_bounds__(256) void s_head0_kernel(
    const float* __restrict__ qkv, float* __restrict__ S)
{
    const int tid = threadIdx.x;
    const int tx = tid & 15, ty = tid >> 4;
    const int s0 = blockIdx.x * 64, t0 = blockIdx.y * 64, b = blockIdx.z;

    if (s0 > t0 + 63) {  // fully above diagonal: zero-fill
        float4 z = make_float4(0.f, 0.f, 0.f, 0.f);
#pragma unroll
        for (int i = 0; i < 4; ++i) {
            int t = t0 + ty * 4 + i;
            *(float4*)(S + ((size_t)b * TT + t) * TT + s0 + tx * 4) = z;
        }
        return;
    }

    __shared__ __align__(16) float As[16][68];
    __shared__ __align__(16) float Bs[16][68];
    float acc[4][4];
#pragma unroll
    for (int i = 0; i < 4; ++i)
#pragma unroll
        for (int j = 0; j < 4; ++j) acc[i][j] = 0.f;

    for (int k0 = 0; k0 < 64; k0 += 16) {
        int r = tid >> 2, c = (tid & 3) * 4;
        float4 av = *(const float4*)(qkv + ((size_t)b * TT + t0 + r) * QKVN + k0 + c);
        As[c + 0][r] = av.x; As[c + 1][r] = av.y;
        As[c + 2][r] = av.z; As[c + 3][r] = av.w;
        float4 bv = *(const float4*)(qkv + ((size_t)b * TT + s0 + r) * QKVN + 768 + k0 + c);
        Bs[c + 0][r] = bv.x; Bs[c + 1][r] = bv.y;
        Bs[c + 2][r] = bv.z; Bs[c + 3][r] = bv.w;
        __syncthreads();
#pragma unroll
        for (int kk = 0; kk < 16; ++kk) {
            float4 a4 = *(const float4*)&As[kk][ty * 4];
            float4 b4 = *(const float4*)&Bs[kk][tx * 4];
            float a[4] = {a4.x, a4.y, a4.z, a4.w};
            float bb[4] = {b4.x, b4.y, b4.z, b4.w};
#pragma unroll
            for (int i = 0; i < 4; ++i)
#pragma unroll
                for (int j = 0; j < 4; ++j)
                    acc[i][j] = fmaf(a[i], bb[j], acc[i][j]);
        }
        __syncthreads();
    }

#pragma unroll
    for (int i = 0; i < 4; ++i) {
        int t = t0 + ty * 4 + i;
        int sb = s0 + tx * 4;
        float4 o;
        o.x = (sb + 0 > 0 && sb + 0 < t) ? fmaxf(acc[i][0] * 0.125f, 0.f) : 0.f;
        o.y = (sb + 1 > 0 && sb + 1 < t) ? fmaxf(acc[i][1] * 0.125f, 0.f) : 0.f;
        o.z = (sb + 2 > 0 && sb + 2 < t) ? fmaxf(acc[i][2] * 0.125f, 0.f) : 0.f;
        o.w = (sb + 3 > 0 && sb + 3 < t) ? fmaxf(acc[i][3] * 0.125f, 0.f) : 0.f;
        *(float4*)(S + ((size_t)b * TT + t) * TT + sb) = o;
    }
}

// ---------------------------------------------- segmented exclusive scan (t)
__global__ void scan_pass1(const float* __restrict__ S, float* __restrict__ gsum)
{
    int s = blockIdx.x * 256 + threadIdx.x;
    int g = blockIdx.y, b = blockIdx.z;
    const float* base = S + ((size_t)b * TT + g * 128) * TT + s;
    float acc = 0.f;
#pragma unroll 4
    for (int r = 0; r < 128; ++r) acc += base[(size_t)r * TT];
    gsum[((size_t)b * 16 + g) * TT + s] = acc;
}

__global__ void scan_pass2(float* __restrict__ gsum)
{
    int idx = blockIdx.x * 256 + threadIdx.x;  // 0..4095
    int b = idx >> 11, s = idx & 2047;
    float acc = 0.f;
#pragma unroll
    for (int g = 0; g < 16; ++g) {
        size_t a = ((size_t)b * 16 + g) * TT + s;
        float v = gsum[a];
        gsum[a] = acc;
        acc += v;
    }
}

__global__ void scan_pass3(float* __restrict__ S, const float* __restrict__ gsum)
{
    int s = blockIdx.x * 256 + threadIdx.x;
    int g = blockIdx.y, b = blockIdx.z;
    float acc = gsum[((size_t)b * 16 + g) * TT + s];
    float* base = S + ((size_t)b * TT + g * 128) * TT + s;
#pragma unroll 4
    for (int r = 0; r < 128; ++r) {
        float v = base[(size_t)r * TT];
        base[(size_t)r * TT] = acc;
        acc += v;
    }
}

// ------------------------------------------------- FF_sum[b,t] = sum clip(FF)
__global__ void ffsum_kernel(const float* __restrict__ FF, float* __restrict__ FS)
{
    int row = blockIdx.x;  // b*TT + t
    int tid = threadIdx.x;
    const float* p = FF + (size_t)row * TT;
    float acc = 0.f;
#pragma unroll
    for (int s = tid; s < TT; s += 256) {
        float v = p[s];
        acc += fminf(fmaxf(v, 0.f), 1.f);
    }
#pragma unroll
    for (int off = 32; off > 0; off >>= 1) acc += __shfl_down(acc, off, 64);
    __shared__ float red[4];
    if ((tid & 63) == 0) red[tid >> 6] = acc;
    __syncthreads();
    if (tid == 0) FS[row] = (red[0] + red[1]) + (red[2] + red[3]);
}

// ----------------------------------------------------- M[0,b,i,j] = i - FS[b,j]
__global__ void mout_kernel(const float* __restrict__ FS, float* __restrict__ Mo)
{
    size_t idx = (size_t)blockIdx.x * 256 + threadIdx.x;
    int j = (int)(idx & 2047);
    int i = (int)((idx >> 11) & 2047);
    int b = (int)(idx >> 22);
    Mo[idx] = (float)i - FS[b * TT + j];
}

// -------------------------------------------- flash attention with FF penalty
// v2: 256-thread blocks (4 waves). Wave w handles KV 16-tiles congruent to w
// mod 4 (exactly tt+1 each, so __syncthreads counts match). Per-wave flash
// state merged in LDS epilogue. 1-D grid with XOR-fold swizzle so the 3
// resident blocks per CU get decorrelated tile depths (resident-stride is a
// multiple of 32, which a linear map cannot decorrelate).
__global__ __launch_bounds__(256) void attn_kernel(
    const float* __restrict__ qkv, const float* __restrict__ FF,
    float* __restrict__ Y)
{
    const int sblk = blockIdx.x;           // 0..767
    const int hi = sblk >> 5;              // 0..23
    const int lo = (sblk ^ hi) & 31;       // bijective fold per 32-group
    const int tt = lo;
    const int h = hi % NHD;
    const int b = hi / NHD;

    const int tid = threadIdx.x;
    const int w = tid >> 6, lane = tid & 63;
    const int t = tt * 64 + lane;

    __shared__ __align__(16) float4 Ks[4][16][16];   // [wave][kvrow][c]
    __shared__ __align__(16) float4 Vs[4][16][16];
    __shared__ float m4[4][64], l4[4][64];
    __shared__ float obuf[64][65];

    float q[64];
    {
        const float* qp = qkv + ((size_t)(b * TT + t)) * QKVN + h * 64;
#pragma unroll
        for (int c = 0; c < 16; ++c) {
            float4 v = *(const float4*)(qp + c * 4);
            q[c * 4 + 0] = v.x; q[c * 4 + 1] = v.y;
            q[c * 4 + 2] = v.z; q[c * 4 + 3] = v.w;
        }
    }
    float o[64];
#pragma unroll
    for (int d = 0; d < 64; ++d) o[d] = 0.f;
    float mx = -3.0e38f, l = 0.f;

    const float* ffrow = FF + (size_t)(b * TT + t) * TT;
    const int nit = tt + 1;   // per-wave tiles

#pragma unroll 1
    for (int it = 0; it < nit; ++it) {
        const int s0 = it * 64 + w * 16;
        __syncthreads();
#pragma unroll
        for (int u = 0; u < 4; ++u) {
            int f = u * 64 + lane;
            int r = f >> 4, c = f & 15;
            size_t base = ((size_t)(b * TT) + s0 + r) * QKVN + h * 64 + c * 4;
            Ks[w][r][c] = *(const float4*)(qkv + base + 768);
            Vs[w][r][c] = *(const float4*)(qkv + base + 1536);
        }
        __syncthreads();

        float ff[16];
#pragma unroll
        for (int u = 0; u < 4; ++u) {
            float4 f4 = *(const float4*)(ffrow + s0 + u * 4);
            ff[u * 4 + 0] = f4.x; ff[u * 4 + 1] = f4.y;
            ff[u * 4 + 2] = f4.z; ff[u * 4 + 3] = f4.w;
        }

        float sc[16];
        float mnew = mx;
#pragma unroll
        for (int j = 0; j < 16; ++j) {
            int s = s0 + j;
            float d0 = 0.f, d1 = 0.f, d2 = 0.f, d3 = 0.f;
#pragma unroll
            for (int c = 0; c < 16; ++c) {
                float4 kv = Ks[w][j][c];
                d0 = fmaf(q[c * 4 + 0], kv.x, d0);
                d1 = fmaf(q[c * 4 + 1], kv.y, d1);
                d2 = fmaf(q[c * 4 + 2], kv.z, d2);
                d3 = fmaf(q[c * 4 + 3], kv.w, d3);
            }
            float dot = (d0 + d1) + (d2 + d3);
            sc[j] = (s <= t) ? (dot * 0.125f - ff[j]) : -3.0e38f;
            mnew = fmaxf(mnew, sc[j]);
        }

        float scale = __expf(mx - mnew);
        l *= scale;
#pragma unroll
        for (int d = 0; d < 64; ++d) o[d] *= scale;
        mx = mnew;

#pragma unroll
        for (int j = 0; j < 16; ++j) {
            float p = __expf(sc[j] - mx);
            l += p;
#pragma unroll
            for (int c = 0; c < 16; ++c) {
                float4 vv = Vs[w][j][c];
                o[c * 4 + 0] = fmaf(p, vv.x, o[c * 4 + 0]);
                o[c * 4 + 1] = fmaf(p, vv.y, o[c * 4 + 1]);
                o[c * 4 + 2] = fmaf(p, vv.z, o[c * 4 + 2]);
                o[c * 4 + 3] = fmaf(p, vv.w, o[c * 4 + 3]);
            }
        }
    }

    // ---- merge 4 per-wave partials (flash-decode style) ----
    m4[w][lane] = mx; l4[w][lane] = l;
    __syncthreads();
    float M = fmaxf(fmaxf(m4[0][lane], m4[1][lane]),
                    fmaxf(m4[2][lane], m4[3][lane]));
    float L = l4[0][lane] * __expf(m4[0][lane] - M)
            + l4[1][lane] * __expf(m4[1][lane] - M)
            + l4[2][lane] * __expf(m4[2][lane] - M)
            + l4[3][lane] * __expf(m4[3][lane] - M);
    float sw = __expf(mx - M);

    if (w == 0) {
#pragma unroll
        for (int d = 0; d < 64; ++d) obuf[lane][d] = sw * o[d];
    }
    __syncthreads();
    if (w == 1) {
#pragma unroll
        for (int d = 0; d < 64; ++d) obuf[lane][d] += sw * o[d];
    }
    __syncthreads();
    if (w == 2) {
#pragma unroll
        for (int d = 0; d < 64; ++d) obuf[lane][d] += sw * o[d];
    }
    __syncthreads();
    if (w == 3) {
#pragma unroll
        for (int d = 0; d < 64; ++d) obuf[lane][d] += sw * o[d];
    }
    __syncthreads();

    if (w == 0) {
        const float inv = 1.0f / L;
        float* yo = Y + (size_t)(b * TT + t) * TC + h * 64;
#pragma unroll
        for (int c = 0; c < 16; ++c) {
            float4 v;
            v.x = obuf[lane][c * 4 + 0] * inv;
            v.y = obuf[lane][c * 4 + 1] * inv;
            v.z = obuf[lane][c * 4 + 2] * inv;
            v.w = obuf[lane][c * 4 + 3] * inv;
            *(float4*)(yo + c * 4) = v;
        }
    }
}

// ---------------------------------------------------------------------- launch
extern "C" void kernel_launch(void* const* d_in, const int* in_sizes, int n_in,
                              void* d_out, int out_size, void* d_ws, size_t ws_size,
                              hipStream_t stream)
{
    const float* x      = (const float*)d_in[0];
    const float* W_attn = (const float*)d_in[1];
    const float* b_attn = (const float*)d_in[2];
    const float* W_proj = (const float*)d_in[3];
    const float* b_proj = (const float*)d_in[4];
    float* out = (float*)d_out;
    float* ws  = (float*)d_ws;

    float* qkv  = ws;                 // [4096, 2304]
    float* FFb  = ws + FF_OFF;        // [B, T, T]   S -> FF in place
    float* gsum = ws + GSUM_OFF;      // [B, 16, T]
    float* fsum = ws + FSUM_OFF;      // [B, T]
    float* yatt = ws + YATT_OFF;      // [4096, 768]

    gemm_f32_128<<<dim3(QKVN / 128, BTM / 128), dim3(256), 0, stream>>>(
        x, W_attn, b_attn, qkv, BTM, QKVN, TC);

    s_head0_kernel<<<dim3(TT / 64, TT / 64, TB), dim3(256), 0, stream>>>(qkv, FFb);

    scan_pass1<<<dim3(TT / 256, 16, TB), dim3(256), 0, stream>>>(FFb, gsum);
    scan_pass2<<<dim3(TB * TT / 256), dim3(256), 0, stream>>>(gsum);
    scan_pass3<<<dim3(TT / 256, 16, TB), dim3(256), 0, stream>>>(FFb, gsum);

    ffsum_kernel<<<dim3(TB * TT), dim3(256), 0, stream>>>(FFb, fsum);

    attn_kernel<<<dim3(TT / 64 * NHD * TB), dim3(256), 0, stream>>>(qkv, FFb, yatt);

    gemm_f32_128<<<dim3(TC / 128, BTM / 128), dim3(256), 0, stream>>>(
        yatt, W_proj, b_proj, out, BTM, TC, TC);

    mout_kernel<<<dim3((unsigned)((size_t)TB * TT * TT / 256)), dim3(256), 0, stream>>>(
        fsum, out + YSZ);
}

// Round 3
// 745.146 us; speedup vs baseline: 3.3923x; 1.8696x over previous
//
#include <hip/hip_runtime.h>
#include <cstddef>

#define TB   2
#define TT   2048
#define TC   768
#define NHD  12
#define HDD  64
#define QKVN 2304
#define BTM  4096   // TB*TT

// ws layout (float offsets); total 21,041,152 floats = 84.2 MB
#define FF_OFF   9437184ull    // BTM*QKVN
#define GSUM_OFF 17825792ull   // + TB*TT*TT
#define FSUM_OFF 17891328ull   // + TB*16*TT
#define YATT_OFF 17895424ull   // + TB*TT
#define YSZ      3145728       // BTM*TC

// ---------------------------------------------------------------- GEMM 128x128
// C[M,N] = A[M,K] @ W[K,N] + bias[N]; M,N multiples of 128, K multiple of 16.
__global__ __launch_bounds__(256) void gemm_f32_128(
    const float* __restrict__ A, const float* __restrict__ W,
    const float* __restrict__ bias, float* __restrict__ Co,
    int M, int N, int K)
{
    __shared__ __align__(16) float As[16][132];
    __shared__ __align__(16) float Bs[16][132];
    const int tid = threadIdx.x;
    const int tx = tid & 15, ty = tid >> 4;
    const int row0 = blockIdx.y * 128, col0 = blockIdx.x * 128;

    float acc[8][8];
#pragma unroll
    for (int i = 0; i < 8; ++i)
#pragma unroll
        for (int j = 0; j < 8; ++j) acc[i][j] = 0.f;

    for (int k0 = 0; k0 < K; k0 += 16) {
#pragma unroll
        for (int u = 0; u < 2; ++u) {
            int f4 = tid * 2 + u;
            int ra = f4 >> 2, ca = (f4 & 3) * 4;
            float4 av = *(const float4*)(A + (size_t)(row0 + ra) * K + k0 + ca);
            As[ca + 0][ra] = av.x; As[ca + 1][ra] = av.y;
            As[ca + 2][ra] = av.z; As[ca + 3][ra] = av.w;
            int rb = f4 >> 5, cb = (f4 & 31) * 4;
            float4 bv = *(const float4*)(W + (size_t)(k0 + rb) * N + col0 + cb);
            *(float4*)&Bs[rb][cb] = bv;
        }
        __syncthreads();
#pragma unroll
        for (int kk = 0; kk < 16; ++kk) {
            float4 t0 = *(const float4*)&As[kk][ty * 4];
            float4 t1 = *(const float4*)&As[kk][64 + ty * 4];
            float4 t2 = *(const float4*)&Bs[kk][tx * 4];
            float4 t3 = *(const float4*)&Bs[kk][64 + tx * 4];
            float a[8], bq[8];
            a[0]=t0.x; a[1]=t0.y; a[2]=t0.z; a[3]=t0.w;
            a[4]=t1.x; a[5]=t1.y; a[6]=t1.z; a[7]=t1.w;
            bq[0]=t2.x; bq[1]=t2.y; bq[2]=t2.z; bq[3]=t2.w;
            bq[4]=t3.x; bq[5]=t3.y; bq[6]=t3.z; bq[7]=t3.w;
#pragma unroll
            for (int i = 0; i < 8; ++i)
#pragma unroll
                for (int j = 0; j < 8; ++j)
                    acc[i][j] = fmaf(a[i], bq[j], acc[i][j]);
        }
        __syncthreads();
    }

    float4 bi0 = *(const float4*)(bias + col0 + tx * 4);
    float4 bi1 = *(const float4*)(bias + col0 + 64 + tx * 4);
#pragma unroll
    for (int ih = 0; ih < 2; ++ih)
#pragma unroll
        for (int i = 0; i < 4; ++i) {
            int r = row0 + ih * 64 + ty * 4 + i;
            int ai = ih * 4 + i;
            float4 c0, c1;
            c0.x = acc[ai][0] + bi0.x; c0.y = acc[ai][1] + bi0.y;
            c0.z = acc[ai][2] + bi0.z; c0.w = acc[ai][3] + bi0.w;
            c1.x = acc[ai][4] + bi1.x; c1.y = acc[ai][5] + bi1.y;
            c1.z = acc[ai][6] + bi1.z; c1.w = acc[ai][7] + bi1.w;
            *(float4*)(Co + (size_t)r * N + col0 + tx * 4) = c0;
            *(float4*)(Co + (size_t)r * N + col0 + 64 + tx * 4) = c1;
        }
}

// ------------------------------------------------- head-0 selection scores S
// S[b,t,s] = (0<s && s<t) ? max(q0[t].k0[s]/8, 0) : 0   (full matrix written)
__global__ __launch_bounds__(256) void s_head0_kernel(
    const float* __restrict__ qkv, float* __restrict__ S)
{
    const int tid = threadIdx.x;
    const int tx = tid & 15, ty = tid >> 4;
    const int s0 = blockIdx.x * 64, t0 = blockIdx.y * 64, b = blockIdx.z;

    if (s0 > t0 + 63) {  // fully above diagonal: zero-fill
        float4 z = make_float4(0.f, 0.f, 0.f, 0.f);
#pragma unroll
        for (int i = 0; i < 4; ++i) {
            int t = t0 + ty * 4 + i;
            *(float4*)(S + ((size_t)b * TT + t) * TT + s0 + tx * 4) = z;
        }
        return;
    }

    __shared__ __align__(16) float As[16][68];
    __shared__ __align__(16) float Bs[16][68];
    float acc[4][4];
#pragma unroll
    for (int i = 0; i < 4; ++i)
#pragma unroll
        for (int j = 0; j < 4; ++j) acc[i][j] = 0.f;

    for (int k0 = 0; k0 < 64; k0 += 16) {
        int r = tid >> 2, c = (tid & 3) * 4;
        float4 av = *(const float4*)(qkv + ((size_t)b * TT + t0 + r) * QKVN + k0 + c);
        As[c + 0][r] = av.x; As[c + 1][r] = av.y;
        As[c + 2][r] = av.z; As[c + 3][r] = av.w;
        float4 bv = *(const float4*)(qkv + ((size_t)b * TT + s0 + r) * QKVN + 768 + k0 + c);
        Bs[c + 0][r] = bv.x; Bs[c + 1][r] = bv.y;
        Bs[c + 2][r] = bv.z; Bs[c + 3][r] = bv.w;
        __syncthreads();
#pragma unroll
        for (int kk = 0; kk < 16; ++kk) {
            float4 a4 = *(const float4*)&As[kk][ty * 4];
            float4 b4 = *(const float4*)&Bs[kk][tx * 4];
            float a[4] = {a4.x, a4.y, a4.z, a4.w};
            float bb[4] = {b4.x, b4.y, b4.z, b4.w};
#pragma unroll
            for (int i = 0; i < 4; ++i)
#pragma unroll
                for (int j = 0; j < 4; ++j)
                    acc[i][j] = fmaf(a[i], bb[j], acc[i][j]);
        }
        __syncthreads();
    }

#pragma unroll
    for (int i = 0; i < 4; ++i) {
        int t = t0 + ty * 4 + i;
        int sb = s0 + tx * 4;
        float4 o;
        o.x = (sb + 0 > 0 && sb + 0 < t) ? fmaxf(acc[i][0] * 0.125f, 0.f) : 0.f;
        o.y = (sb + 1 > 0 && sb + 1 < t) ? fmaxf(acc[i][1] * 0.125f, 0.f) : 0.f;
        o.z = (sb + 2 > 0 && sb + 2 < t) ? fmaxf(acc[i][2] * 0.125f, 0.f) : 0.f;
        o.w = (sb + 3 > 0 && sb + 3 < t) ? fmaxf(acc[i][3] * 0.125f, 0.f) : 0.f;
        *(float4*)(S + ((size_t)b * TT + t) * TT + sb) = o;
    }
}

// ---------------------------------------------- segmented exclusive scan (t)
__global__ void scan_pass1(const float* __restrict__ S, float* __restrict__ gsum)
{
    int s = blockIdx.x * 256 + threadIdx.x;
    int g = blockIdx.y, b = blockIdx.z;
    const float* base = S + ((size_t)b * TT + g * 128) * TT + s;
    float acc = 0.f;
#pragma unroll 4
    for (int r = 0; r < 128; ++r) acc += base[(size_t)r * TT];
    gsum[((size_t)b * 16 + g) * TT + s] = acc;
}

__global__ void scan_pass2(float* __restrict__ gsum)
{
    int idx = blockIdx.x * 256 + threadIdx.x;  // 0..4095
    int b = idx >> 11, s = idx & 2047;
    float acc = 0.f;
#pragma unroll
    for (int g = 0; g < 16; ++g) {
        size_t a = ((size_t)b * 16 + g) * TT + s;
        float v = gsum[a];
        gsum[a] = acc;
        acc += v;
    }
}

__global__ void scan_pass3(float* __restrict__ S, const float* __restrict__ gsum)
{
    int s = blockIdx.x * 256 + threadIdx.x;
    int g = blockIdx.y, b = blockIdx.z;
    float acc = gsum[((size_t)b * 16 + g) * TT + s];
    float* base = S + ((size_t)b * TT + g * 128) * TT + s;
#pragma unroll 4
    for (int r = 0; r < 128; ++r) {
        float v = base[(size_t)r * TT];
        base[(size_t)r * TT] = acc;
        acc += v;
    }
}

// ------------------------------------------------- FF_sum[b,t] = sum clip(FF)
__global__ void ffsum_kernel(const float* __restrict__ FF, float* __restrict__ FS)
{
    int row = blockIdx.x;  // b*TT + t
    int tid = threadIdx.x;
    const float* p = FF + (size_t)row * TT;
    float acc = 0.f;
#pragma unroll
    for (int s = tid; s < TT; s += 256) {
        float v = p[s];
        acc += fminf(fmaxf(v, 0.f), 1.f);
    }
#pragma unroll
    for (int off = 32; off > 0; off >>= 1) acc += __shfl_down(acc, off, 64);
    __shared__ float red[4];
    if ((tid & 63) == 0) red[tid >> 6] = acc;
    __syncthreads();
    if (tid == 0) FS[row] = (red[0] + red[1]) + (red[2] + red[3]);
}

// ----------------------------------------------------- M[0,b,i,j] = i - FS[b,j]
__global__ void mout_kernel(const float* __restrict__ FS, float* __restrict__ Mo)
{
    size_t idx = (size_t)blockIdx.x * 256 + threadIdx.x;
    int j = (int)(idx & 2047);
    int i = (int)((idx >> 11) & 2047);
    int b = (int)(idx >> 22);
    Mo[idx] = (float)i - FS[b * TT + j];
}

// -------------------------------------------- flash attention with FF penalty
// v3: GEMM-structured. Block = 64 q-rows of one (b,h); 256 threads; thread
// (ty,tx) owns a 4x4 tile of the 64x64 score matrix (rows ty*4+i, cols
// tx*4+j). QK^T and PV are register outer products (2 ds_read_b128 -> 16
// fma per k). P round-trips through LDS aliased onto the K^T buffer.
// Online softmax per row via shfl_xor within 16-lane ty-groups.
__global__ __launch_bounds__(256) void attn_kernel(
    const float* __restrict__ qkv, const float* __restrict__ FF,
    float* __restrict__ Y)
{
    const int sblk = blockIdx.x;           // 0..767
    const int hi = sblk >> 5;              // 0..23
    const int tt = (sblk ^ hi) & 31;       // bijective fold per 32-group
    const int h = hi % NHD;
    const int b = hi / NHD;

    const int tid = threadIdx.x;
    const int tx = tid & 15, ty = tid >> 4;
    const int t0 = tt * 64;

    __shared__ __align__(16) float Qs[64][68];   // Q^T: Qs[d][r]
    __shared__ __align__(16) float Ks[64][68];   // K^T: Ks[d][s]; reused as P^T: Ps[s][r]
    __shared__ __align__(16) float Vs[64][68];   // V:   Vs[s][d]

    // ---- stage Q transposed (once per block) ----
#pragma unroll
    for (int u = 0; u < 4; ++u) {
        int f = u * 256 + tid;
        int r = f >> 4;            // 0..63
        int c = (f & 15) * 4;      // 0..60
        float4 qv = *(const float4*)(qkv + ((size_t)(b * TT) + t0 + r) * QKVN + h * 64 + c);
        Qs[c + 0][r] = qv.x; Qs[c + 1][r] = qv.y;
        Qs[c + 2][r] = qv.z; Qs[c + 3][r] = qv.w;
    }

    float oacc[4][4];
    float m_i[4], l_i[4];
#pragma unroll
    for (int i = 0; i < 4; ++i) {
        m_i[i] = -3.0e38f; l_i[i] = 0.f;
#pragma unroll
        for (int j = 0; j < 4; ++j) oacc[i][j] = 0.f;
    }

    const int rbase = t0 + ty * 4;

#pragma unroll 1
    for (int it = 0; it <= tt; ++it) {
        const int s0 = it * 64;
        __syncthreads();   // prior PV done reading Ks/Vs; Q stores visible

        // ---- stage K^T, V ----
#pragma unroll
        for (int u = 0; u < 4; ++u) {
            int f = u * 256 + tid;
            int r = f >> 4;
            int c = (f & 15) * 4;
            size_t base = ((size_t)(b * TT) + s0 + r) * QKVN + h * 64 + c;
            float4 kv = *(const float4*)(qkv + base + 768);
            float4 vv = *(const float4*)(qkv + base + 1536);
            Ks[c + 0][r] = kv.x; Ks[c + 1][r] = kv.y;
            Ks[c + 2][r] = kv.z; Ks[c + 3][r] = kv.w;
            *(float4*)&Vs[r][c] = vv;
        }
        __syncthreads();

        // ---- S = Q K^T (4x4 per thread) ----
        float sacc[4][4];
#pragma unroll
        for (int i = 0; i < 4; ++i)
#pragma unroll
            for (int j = 0; j < 4; ++j) sacc[i][j] = 0.f;

#pragma unroll 4
        for (int k = 0; k < 64; ++k) {
            float4 a4 = *(const float4*)&Qs[k][ty * 4];
            float4 b4 = *(const float4*)&Ks[k][tx * 4];
            float a[4] = {a4.x, a4.y, a4.z, a4.w};
            float bb[4] = {b4.x, b4.y, b4.z, b4.w};
#pragma unroll
            for (int i = 0; i < 4; ++i)
#pragma unroll
                for (int j = 0; j < 4; ++j)
                    sacc[i][j] = fmaf(a[i], bb[j], sacc[i][j]);
        }

        // ---- logits: scale, FF penalty, causal mask (diagonal tile only) ----
        const int cbase = s0 + tx * 4;
#pragma unroll
        for (int i = 0; i < 4; ++i) {
            float4 f4 = *(const float4*)(FF + ((size_t)(b * TT) + rbase + i) * TT + cbase);
            sacc[i][0] = sacc[i][0] * 0.125f - f4.x;
            sacc[i][1] = sacc[i][1] * 0.125f - f4.y;
            sacc[i][2] = sacc[i][2] * 0.125f - f4.z;
            sacc[i][3] = sacc[i][3] * 0.125f - f4.w;
        }
        if (it == tt) {
#pragma unroll
            for (int i = 0; i < 4; ++i)
#pragma unroll
                for (int j = 0; j < 4; ++j)
                    if (cbase + j > rbase + i) sacc[i][j] = -3.0e38f;
        }

        // ---- online softmax (row reductions across the 16-lane ty-group) ----
        float alpha[4];
#pragma unroll
        for (int i = 0; i < 4; ++i) {
            float rm = fmaxf(fmaxf(sacc[i][0], sacc[i][1]),
                             fmaxf(sacc[i][2], sacc[i][3]));
            rm = fmaxf(rm, __shfl_xor(rm, 1, 16));
            rm = fmaxf(rm, __shfl_xor(rm, 2, 16));
            rm = fmaxf(rm, __shfl_xor(rm, 4, 16));
            rm = fmaxf(rm, __shfl_xor(rm, 8, 16));
            float mnew = fmaxf(m_i[i], rm);
            alpha[i] = __expf(m_i[i] - mnew);
            m_i[i] = mnew;
#pragma unroll
            for (int j = 0; j < 4; ++j)
                sacc[i][j] = __expf(sacc[i][j] - mnew);   // P
            float rs = (sacc[i][0] + sacc[i][1]) + (sacc[i][2] + sacc[i][3]);
            rs += __shfl_xor(rs, 1, 16);
            rs += __shfl_xor(rs, 2, 16);
            rs += __shfl_xor(rs, 4, 16);
            rs += __shfl_xor(rs, 8, 16);
            l_i[i] = l_i[i] * alpha[i] + rs;
#pragma unroll
            for (int j = 0; j < 4; ++j) oacc[i][j] *= alpha[i];
        }

        __syncthreads();   // all waves done reading Ks (QK phase)
        // ---- store P^T into Ks buffer: Ps[s][r] ----
#pragma unroll
        for (int i = 0; i < 4; ++i)
#pragma unroll
            for (int j = 0; j < 4; ++j)
                Ks[tx * 4 + j][ty * 4 + i] = sacc[i][j];
        __syncthreads();

        // ---- O += P V (4x4 per thread) ----
#pragma unroll 4
        for (int k = 0; k < 64; ++k) {
            float4 p4 = *(const float4*)&Ks[k][ty * 4];
            float4 v4 = *(const float4*)&Vs[k][tx * 4];
            float p[4] = {p4.x, p4.y, p4.z, p4.w};
            float vv[4] = {v4.x, v4.y, v4.z, v4.w};
#pragma unroll
            for (int i = 0; i < 4; ++i)
#pragma unroll
                for (int j = 0; j < 4; ++j)
                    oacc[i][j] = fmaf(p[i], vv[j], oacc[i][j]);
        }
    }

    // ---- epilogue ----
#pragma unroll
    for (int i = 0; i < 4; ++i) {
        const float inv = 1.0f / l_i[i];
        float4 v;
        v.x = oacc[i][0] * inv; v.y = oacc[i][1] * inv;
        v.z = oacc[i][2] * inv; v.w = oacc[i][3] * inv;
        *(float4*)(Y + ((size_t)(b * TT) + rbase + i) * TC + h * 64 + tx * 4) = v;
    }
}

// ---------------------------------------------------------------------- launch
extern "C" void kernel_launch(void* const* d_in, const int* in_sizes, int n_in,
                              void* d_out, int out_size, void* d_ws, size_t ws_size,
                              hipStream_t stream)
{
    const float* x      = (const float*)d_in[0];
    const float* W_attn = (const float*)d_in[1];
    const float* b_attn = (const float*)d_in[2];
    const float* W_proj = (const float*)d_in[3];
    const float* b_proj = (const float*)d_in[4];
    float* out = (float*)d_out;
    float* ws  = (float*)d_ws;

    float* qkv  = ws;                 // [4096, 2304]
    float* FFb  = ws + FF_OFF;        // [B, T, T]   S -> FF in place
    float* gsum = ws + GSUM_OFF;      // [B, 16, T]
    float* fsum = ws + FSUM_OFF;      // [B, T]
    float* yatt = ws + YATT_OFF;      // [4096, 768]

    gemm_f32_128<<<dim3(QKVN / 128, BTM / 128), dim3(256), 0, stream>>>(
        x, W_attn, b_attn, qkv, BTM, QKVN, TC);

    s_head0_kernel<<<dim3(TT / 64, TT / 64, TB), dim3(256), 0, stream>>>(qkv, FFb);

    scan_pass1<<<dim3(TT / 256, 16, TB), dim3(256), 0, stream>>>(FFb, gsum);
    scan_pass2<<<dim3(TB * TT / 256), dim3(256), 0, stream>>>(gsum);
    scan_pass3<<<dim3(TT / 256, 16, TB), dim3(256), 0, stream>>>(FFb, gsum);

    ffsum_kernel<<<dim3(TB * TT), dim3(256), 0, stream>>>(FFb, fsum);

    attn_kernel<<<dim3(TT / 64 * NHD * TB), dim3(256), 0, stream>>>(qkv, FFb, yatt);

    gemm_f32_128<<<dim3(TC / 128, BTM / 128), dim3(256), 0, stream>>>(
        yatt, W_proj, b_proj, out, BTM, TC, TC);

    mout_kernel<<<dim3((unsigned)((size_t)TB * TT * TT / 256)), dim3(256), 0, stream>>>(
        fsum, out + YSZ);
}

// Round 4
// 470.794 us; speedup vs baseline: 5.3692x; 1.5827x over previous
//
#include <hip/hip_runtime.h>
#include <cstddef>

#define TB   2
#define TT   2048
#define TC   768
#define NHD  12
#define HDD  64
#define QKVN 2304
#define BTM  4096   // TB*TT

// ws layout (float offsets); total 21,041,152 floats = 84.2 MB
#define FF_OFF   9437184ull    // BTM*QKVN
#define GSUM_OFF 17825792ull   // + TB*TT*TT
#define FSUM_OFF 17891328ull   // + TB*16*TT
#define YATT_OFF 17895424ull   // + TB*TT
#define YSZ      3145728       // BTM*TC

typedef __attribute__((ext_vector_type(8))) short bf16x8;
typedef __attribute__((ext_vector_type(4))) float f32x4;

__device__ inline unsigned short f2bf(float f) {
    unsigned u = __float_as_uint(f);
    return (unsigned short)((u + 0x7fffu + ((u >> 16) & 1u)) >> 16);
}

// ------------------------------------------------------- fp32 -> bf16 cast
__global__ __launch_bounds__(256) void castbf(
    const float* __restrict__ in, unsigned short* __restrict__ out, int n8)
{
    int idx = blockIdx.x * 256 + threadIdx.x;
    if (idx >= n8) return;
    const float4* p = (const float4*)(in + (size_t)idx * 8);
    float4 a = p[0], b = p[1];
    union { unsigned short us[8]; uint4 u4; } r;
    r.us[0] = f2bf(a.x); r.us[1] = f2bf(a.y); r.us[2] = f2bf(a.z); r.us[3] = f2bf(a.w);
    r.us[4] = f2bf(b.x); r.us[5] = f2bf(b.y); r.us[6] = f2bf(b.z); r.us[7] = f2bf(b.w);
    *(uint4*)(out + (size_t)idx * 8) = r.u4;
}

// ------------------------------------- W[K][N] fp32 -> Wt[N][K] bf16 (64x64)
__global__ __launch_bounds__(256) void tcast(
    const float* __restrict__ W, unsigned short* __restrict__ Wt, int K, int N)
{
    __shared__ unsigned short T[64][80];   // row 160B, 16B-aligned rows
    const int tid = threadIdx.x;
    const int k0 = blockIdx.x * 64, n0 = blockIdx.y * 64;
#pragma unroll
    for (int u = 0; u < 4; ++u) {
        int f = u * 256 + tid;           // 0..1023
        int kr = f >> 4, nc = (f & 15) * 4;
        float4 v = *(const float4*)(W + (size_t)(k0 + kr) * N + n0 + nc);
        T[nc + 0][kr] = f2bf(v.x); T[nc + 1][kr] = f2bf(v.y);
        T[nc + 2][kr] = f2bf(v.z); T[nc + 3][kr] = f2bf(v.w);
    }
    __syncthreads();
#pragma unroll
    for (int u = 0; u < 2; ++u) {
        int f = u * 256 + tid;           // 0..511
        int nr = f >> 3, kc = (f & 7) * 8;
        *(uint4*)(Wt + (size_t)(n0 + nr) * K + k0 + kc) = *(uint4*)&T[nr][kc];
    }
}

// --------------------------------------------------------- bf16 MFMA GEMM
// C[M,N] = A[M,K] @ Bt[N,K]^T + bias[N]; fp32 out. 128x128 tile, BK=64,
// 4 waves, each wave a 64x64 quadrant of 4x4 MFMA 16x16x32_bf16 tiles.
// LDS XOR-swizzle (kq ^= row&7) -> staging writes and fragment reads both
// 2-way bank aliasing (free on CDNA4).
__global__ __launch_bounds__(256) void gemm_bf16(
    const unsigned short* __restrict__ A, const unsigned short* __restrict__ Bt,
    const float* __restrict__ bias, float* __restrict__ C,
    int M, int N, int K)
{
    __shared__ unsigned short As[128 * 64];
    __shared__ unsigned short Bs[128 * 64];
    const int tid = threadIdx.x;
    const int w = tid >> 6, lane = tid & 63;
    const int row0 = blockIdx.y * 128, col0 = blockIdx.x * 128;
    const int moff = (w >> 1) * 64, noff = (w & 1) * 64;
    const int lm = lane & 15, quad = lane >> 4;

    f32x4 acc[4][4];
#pragma unroll
    for (int i = 0; i < 4; ++i)
#pragma unroll
        for (int j = 0; j < 4; ++j) acc[i][j] = (f32x4){0.f, 0.f, 0.f, 0.f};

    for (int k0 = 0; k0 < K; k0 += 64) {
        __syncthreads();
#pragma unroll
        for (int u = 0; u < 4; ++u) {
            int unit = u * 256 + tid;      // 0..1023
            int r = unit >> 3, kq = unit & 7;
            int kqs = kq ^ (r & 7);
            bf16x8 va = *(const bf16x8*)(A + (size_t)(row0 + r) * K + k0 + kq * 8);
            *(bf16x8*)&As[r * 64 + kqs * 8] = va;
            bf16x8 vb = *(const bf16x8*)(Bt + (size_t)(col0 + r) * K + k0 + kq * 8);
            *(bf16x8*)&Bs[r * 64 + kqs * 8] = vb;
        }
        __syncthreads();
#pragma unroll
        for (int kh = 0; kh < 2; ++kh) {
            const int kqb = kh * 4 + quad;
            bf16x8 af[4], bfr[4];
#pragma unroll
            for (int i = 0; i < 4; ++i) {
                int mr = moff + i * 16 + lm;
                af[i] = *(const bf16x8*)&As[mr * 64 + (kqb ^ (mr & 7)) * 8];
                int nr = noff + i * 16 + lm;
                bfr[i] = *(const bf16x8*)&Bs[nr * 64 + (kqb ^ (nr & 7)) * 8];
            }
#pragma unroll
            for (int i = 0; i < 4; ++i)
#pragma unroll
                for (int j = 0; j < 4; ++j)
                    acc[i][j] = __builtin_amdgcn_mfma_f32_16x16x32_bf16(
                        af[i], bfr[j], acc[i][j], 0, 0, 0);
        }
    }

#pragma unroll
    for (int j = 0; j < 4; ++j) {
        int n = col0 + noff + j * 16 + lm;
        float bv = bias[n];
#pragma unroll
        for (int i = 0; i < 4; ++i) {
            int mbase = row0 + moff + i * 16 + quad * 4;
#pragma unroll
            for (int r = 0; r < 4; ++r)
                C[(size_t)(mbase + r) * N + n] = acc[i][j][r] + bv;
        }
    }
}

// ------------------------------------------------- head-0 selection scores S
// S[b,t,s] = (0<s && s<t) ? max(q0[t].k0[s]/8, 0) : 0   (full matrix written)
__global__ __launch_bounds__(256) void s_head0_kernel(
    const float* __restrict__ qkv, float* __restrict__ S)
{
    const int tid = threadIdx.x;
    const int tx = tid & 15, ty = tid >> 4;
    const int s0 = blockIdx.x * 64, t0 = blockIdx.y * 64, b = blockIdx.z;

    if (s0 > t0 + 63) {  // fully above diagonal: zero-fill
        float4 z = make_float4(0.f, 0.f, 0.f, 0.f);
#pragma unroll
        for (int i = 0; i < 4; ++i) {
            int t = t0 + ty * 4 + i;
            *(float4*)(S + ((size_t)b * TT + t) * TT + s0 + tx * 4) = z;
        }
        return;
    }

    __shared__ __align__(16) float As[16][68];
    __shared__ __align__(16) float Bs[16][68];
    float acc[4][4];
#pragma unroll
    for (int i = 0; i < 4; ++i)
#pragma unroll
        for (int j = 0; j < 4; ++j) acc[i][j] = 0.f;

    for (int k0 = 0; k0 < 64; k0 += 16) {
        int r = tid >> 2, c = (tid & 3) * 4;
        float4 av = *(const float4*)(qkv + ((size_t)b * TT + t0 + r) * QKVN + k0 + c);
        As[c + 0][r] = av.x; As[c + 1][r] = av.y;
        As[c + 2][r] = av.z; As[c + 3][r] = av.w;
        float4 bv = *(const float4*)(qkv + ((size_t)b * TT + s0 + r) * QKVN + 768 + k0 + c);
        Bs[c + 0][r] = bv.x; Bs[c + 1][r] = bv.y;
        Bs[c + 2][r] = bv.z; Bs[c + 3][r] = bv.w;
        __syncthreads();
#pragma unroll
        for (int kk = 0; kk < 16; ++kk) {
            float4 a4 = *(const float4*)&As[kk][ty * 4];
            float4 b4 = *(const float4*)&Bs[kk][tx * 4];
            float a[4] = {a4.x, a4.y, a4.z, a4.w};
            float bb[4] = {b4.x, b4.y, b4.z, b4.w};
#pragma unroll
            for (int i = 0; i < 4; ++i)
#pragma unroll
                for (int j = 0; j < 4; ++j)
                    acc[i][j] = fmaf(a[i], bb[j], acc[i][j]);
        }
        __syncthreads();
    }

#pragma unroll
    for (int i = 0; i < 4; ++i) {
        int t = t0 + ty * 4 + i;
        int sb = s0 + tx * 4;
        float4 o;
        o.x = (sb + 0 > 0 && sb + 0 < t) ? fmaxf(acc[i][0] * 0.125f, 0.f) : 0.f;
        o.y = (sb + 1 > 0 && sb + 1 < t) ? fmaxf(acc[i][1] * 0.125f, 0.f) : 0.f;
        o.z = (sb + 2 > 0 && sb + 2 < t) ? fmaxf(acc[i][2] * 0.125f, 0.f) : 0.f;
        o.w = (sb + 3 > 0 && sb + 3 < t) ? fmaxf(acc[i][3] * 0.125f, 0.f) : 0.f;
        *(float4*)(S + ((size_t)b * TT + t) * TT + sb) = o;
    }
}

// ---------------------------------------------- segmented exclusive scan (t)
__global__ void scan_pass1(const float* __restrict__ S, float* __restrict__ gsum)
{
    int s = blockIdx.x * 256 + threadIdx.x;
    int g = blockIdx.y, b = blockIdx.z;
    const float* base = S + ((size_t)b * TT + g * 128) * TT + s;
    float acc = 0.f;
#pragma unroll 4
    for (int r = 0; r < 128; ++r) acc += base[(size_t)r * TT];
    gsum[((size_t)b * 16 + g) * TT + s] = acc;
}

__global__ void scan_pass2(float* __restrict__ gsum)
{
    int idx = blockIdx.x * 256 + threadIdx.x;  // 0..4095
    int b = idx >> 11, s = idx & 2047;
    float acc = 0.f;
#pragma unroll
    for (int g = 0; g < 16; ++g) {
        size_t a = ((size_t)b * 16 + g) * TT + s;
        float v = gsum[a];
        gsum[a] = acc;
        acc += v;
    }
}

__global__ void scan_pass3(float* __restrict__ S, const float* __restrict__ gsum)
{
    int s = blockIdx.x * 256 + threadIdx.x;
    int g = blockIdx.y, b = blockIdx.z;
    float acc = gsum[((size_t)b * 16 + g) * TT + s];
    float* base = S + ((size_t)b * TT + g * 128) * TT + s;
#pragma unroll 4
    for (int r = 0; r < 128; ++r) {
        float v = base[(size_t)r * TT];
        base[(size_t)r * TT] = acc;
        acc += v;
    }
}

// ------------------------------------------------- FF_sum[b,t] = sum clip(FF)
__global__ void ffsum_kernel(const float* __restrict__ FF, float* __restrict__ FS)
{
    int row = blockIdx.x;  // b*TT + t
    int tid = threadIdx.x;
    const float* p = FF + (size_t)row * TT;
    float acc = 0.f;
#pragma unroll
    for (int s = tid; s < TT; s += 256) {
        float v = p[s];
        acc += fminf(fmaxf(v, 0.f), 1.f);
    }
#pragma unroll
    for (int off = 32; off > 0; off >>= 1) acc += __shfl_down(acc, off, 64);
    __shared__ float red[4];
    if ((tid & 63) == 0) red[tid >> 6] = acc;
    __syncthreads();
    if (tid == 0) FS[row] = (red[0] + red[1]) + (red[2] + red[3]);
}

// ----------------------------------------------------- M[0,b,i,j] = i - FS[b,j]
__global__ void mout_kernel(const float* __restrict__ FS, float* __restrict__ Mo)
{
    size_t idx = (size_t)blockIdx.x * 256 + threadIdx.x;
    int j = (int)(idx & 2047);
    int i = (int)((idx >> 11) & 2047);
    int b = (int)(idx >> 22);
    Mo[idx] = (float)i - FS[b * TT + j];
}

// -------------------------------------------- flash attention with FF penalty
// v3: GEMM-structured (unchanged from R3).
__global__ __launch_bounds__(256) void attn_kernel(
    const float* __restrict__ qkv, const float* __restrict__ FF,
    float* __restrict__ Y)
{
    const int sblk = blockIdx.x;           // 0..767
    const int hi = sblk >> 5;              // 0..23
    const int tt = (sblk ^ hi) & 31;       // bijective fold per 32-group
    const int h = hi % NHD;
    const int b = hi / NHD;

    const int tid = threadIdx.x;
    const int tx = tid & 15, ty = tid >> 4;
    const int t0 = tt * 64;

    __shared__ __align__(16) float Qs[64][68];   // Q^T: Qs[d][r]
    __shared__ __align__(16) float Ks[64][68];   // K^T: Ks[d][s]; reused as P^T
    __shared__ __align__(16) float Vs[64][68];   // V:   Vs[s][d]

#pragma unroll
    for (int u = 0; u < 4; ++u) {
        int f = u * 256 + tid;
        int r = f >> 4;
        int c = (f & 15) * 4;
        float4 qv = *(const float4*)(qkv + ((size_t)(b * TT) + t0 + r) * QKVN + h * 64 + c);
        Qs[c + 0][r] = qv.x; Qs[c + 1][r] = qv.y;
        Qs[c + 2][r] = qv.z; Qs[c + 3][r] = qv.w;
    }

    float oacc[4][4];
    float m_i[4], l_i[4];
#pragma unroll
    for (int i = 0; i < 4; ++i) {
        m_i[i] = -3.0e38f; l_i[i] = 0.f;
#pragma unroll
        for (int j = 0; j < 4; ++j) oacc[i][j] = 0.f;
    }

    const int rbase = t0 + ty * 4;

#pragma unroll 1
    for (int it = 0; it <= tt; ++it) {
        const int s0 = it * 64;
        __syncthreads();

#pragma unroll
        for (int u = 0; u < 4; ++u) {
            int f = u * 256 + tid;
            int r = f >> 4;
            int c = (f & 15) * 4;
            size_t base = ((size_t)(b * TT) + s0 + r) * QKVN + h * 64 + c;
            float4 kv = *(const float4*)(qkv + base + 768);
            float4 vv = *(const float4*)(qkv + base + 1536);
            Ks[c + 0][r] = kv.x; Ks[c + 1][r] = kv.y;
            Ks[c + 2][r] = kv.z; Ks[c + 3][r] = kv.w;
            *(float4*)&Vs[r][c] = vv;
        }
        __syncthreads();

        float sacc[4][4];
#pragma unroll
        for (int i = 0; i < 4; ++i)
#pragma unroll
            for (int j = 0; j < 4; ++j) sacc[i][j] = 0.f;

#pragma unroll 4
        for (int k = 0; k < 64; ++k) {
            float4 a4 = *(const float4*)&Qs[k][ty * 4];
            float4 b4 = *(const float4*)&Ks[k][tx * 4];
            float a[4] = {a4.x, a4.y, a4.z, a4.w};
            float bb[4] = {b4.x, b4.y, b4.z, b4.w};
#pragma unroll
            for (int i = 0; i < 4; ++i)
#pragma unroll
                for (int j = 0; j < 4; ++j)
                    sacc[i][j] = fmaf(a[i], bb[j], sacc[i][j]);
        }

        const int cbase = s0 + tx * 4;
#pragma unroll
        for (int i = 0; i < 4; ++i) {
            float4 f4 = *(const float4*)(FF + ((size_t)(b * TT) + rbase + i) * TT + cbase);
            sacc[i][0] = sacc[i][0] * 0.125f - f4.x;
            sacc[i][1] = sacc[i][1] * 0.125f - f4.y;
            sacc[i][2] = sacc[i][2] * 0.125f - f4.z;
            sacc[i][3] = sacc[i][3] * 0.125f - f4.w;
        }
        if (it == tt) {
#pragma unroll
            for (int i = 0; i < 4; ++i)
#pragma unroll
                for (int j = 0; j < 4; ++j)
                    if (cbase + j > rbase + i) sacc[i][j] = -3.0e38f;
        }

        float alpha[4];
#pragma unroll
        for (int i = 0; i < 4; ++i) {
            float rm = fmaxf(fmaxf(sacc[i][0], sacc[i][1]),
                             fmaxf(sacc[i][2], sacc[i][3]));
            rm = fmaxf(rm, __shfl_xor(rm, 1, 16));
            rm = fmaxf(rm, __shfl_xor(rm, 2, 16));
            rm = fmaxf(rm, __shfl_xor(rm, 4, 16));
            rm = fmaxf(rm, __shfl_xor(rm, 8, 16));
            float mnew = fmaxf(m_i[i], rm);
            alpha[i] = __expf(m_i[i] - mnew);
            m_i[i] = mnew;
#pragma unroll
            for (int j = 0; j < 4; ++j)
                sacc[i][j] = __expf(sacc[i][j] - mnew);   // P
            float rs = (sacc[i][0] + sacc[i][1]) + (sacc[i][2] + sacc[i][3]);
            rs += __shfl_xor(rs, 1, 16);
            rs += __shfl_xor(rs, 2, 16);
            rs += __shfl_xor(rs, 4, 16);
            rs += __shfl_xor(rs, 8, 16);
            l_i[i] = l_i[i] * alpha[i] + rs;
#pragma unroll
            for (int j = 0; j < 4; ++j) oacc[i][j] *= alpha[i];
        }

        __syncthreads();
#pragma unroll
        for (int i = 0; i < 4; ++i)
#pragma unroll
            for (int j = 0; j < 4; ++j)
                Ks[tx * 4 + j][ty * 4 + i] = sacc[i][j];
        __syncthreads();

#pragma unroll 4
        for (int k = 0; k < 64; ++k) {
            float4 p4 = *(const float4*)&Ks[k][ty * 4];
            float4 v4 = *(const float4*)&Vs[k][tx * 4];
            float p[4] = {p4.x, p4.y, p4.z, p4.w};
            float vv[4] = {v4.x, v4.y, v4.z, v4.w};
#pragma unroll
            for (int i = 0; i < 4; ++i)
#pragma unroll
                for (int j = 0; j < 4; ++j)
                    oacc[i][j] = fmaf(p[i], vv[j], oacc[i][j]);
        }
    }

#pragma unroll
    for (int i = 0; i < 4; ++i) {
        const float inv = 1.0f / l_i[i];
        float4 v;
        v.x = oacc[i][0] * inv; v.y = oacc[i][1] * inv;
        v.z = oacc[i][2] * inv; v.w = oacc[i][3] * inv;
        *(float4*)(Y + ((size_t)(b * TT) + rbase + i) * TC + h * 64 + tx * 4) = v;
    }
}

// ---------------------------------------------------------------------- launch
extern "C" void kernel_launch(void* const* d_in, const int* in_sizes, int n_in,
                              void* d_out, int out_size, void* d_ws, size_t ws_size,
                              hipStream_t stream)
{
    const float* x      = (const float*)d_in[0];
    const float* W_attn = (const float*)d_in[1];
    const float* b_attn = (const float*)d_in[2];
    const float* W_proj = (const float*)d_in[3];
    const float* b_proj = (const float*)d_in[4];
    float* out = (float*)d_out;
    float* ws  = (float*)d_ws;

    float* qkv  = ws;                 // [4096, 2304] fp32
    float* FFb  = ws + FF_OFF;        // [B, T, T]   S -> FF in place
    float* gsum = ws + GSUM_OFF;      // [B, 16, T]
    float* fsum = ws + FSUM_OFF;      // [B, T]
    float* yatt = ws + YATT_OFF;      // [4096, 768] fp32

    // bf16 aliases inside the FF region (live ranges disjoint with FF):
    //   phase 1 (before s_head0): xb [4096*768], WtA [2304*768]
    //   phase 2 (after attn):     ytb [4096*768], WtP [768*768]
    unsigned short* xb  = (unsigned short*)(ws + FF_OFF);
    unsigned short* WtA = xb + (size_t)BTM * TC;
    unsigned short* ytb = (unsigned short*)(ws + FF_OFF);
    unsigned short* WtP = ytb + (size_t)BTM * TC;

    castbf<<<dim3(1536), dim3(256), 0, stream>>>(x, xb, BTM * TC / 8);
    tcast<<<dim3(TC / 64, QKVN / 64), dim3(256), 0, stream>>>(W_attn, WtA, TC, QKVN);

    gemm_bf16<<<dim3(QKVN / 128, BTM / 128), dim3(256), 0, stream>>>(
        xb, WtA, b_attn, qkv, BTM, QKVN, TC);

    s_head0_kernel<<<dim3(TT / 64, TT / 64, TB), dim3(256), 0, stream>>>(qkv, FFb);

    scan_pass1<<<dim3(TT / 256, 16, TB), dim3(256), 0, stream>>>(FFb, gsum);
    scan_pass2<<<dim3(TB * TT / 256), dim3(256), 0, stream>>>(gsum);
    scan_pass3<<<dim3(TT / 256, 16, TB), dim3(256), 0, stream>>>(FFb, gsum);

    ffsum_kernel<<<dim3(TB * TT), dim3(256), 0, stream>>>(FFb, fsum);

    attn_kernel<<<dim3(TT / 64 * NHD * TB), dim3(256), 0, stream>>>(qkv, FFb, yatt);

    castbf<<<dim3(1536), dim3(256), 0, stream>>>(yatt, ytb, BTM * TC / 8);
    tcast<<<dim3(TC / 64, TC / 64), dim3(256), 0, stream>>>(W_proj, WtP, TC, TC);

    gemm_bf16<<<dim3(TC / 128, BTM / 128), dim3(256), 0, stream>>>(
        ytb, WtP, b_proj, out, BTM, TC, TC);

    mout_kernel<<<dim3((unsigned)((size_t)TB * TT * TT / 256)), dim3(256), 0, stream>>>(
        fsum, out + YSZ);
}

// Round 5
// 299.625 us; speedup vs baseline: 8.4365x; 1.5713x over previous
//
#include <hip/hip_runtime.h>
#include <cstddef>

#define TB   2
#define TT   2048
#define TC   768
#define NHD  12
#define HDD  64
#define QKVN 2304
#define BTM  4096   // TB*TT

// ws layout (float offsets); total 21,041,152 floats = 84.2 MB
#define FF_OFF   9437184ull    // BTM*QKVN
#define GSUM_OFF 17825792ull   // + TB*TT*TT
#define FSUM_OFF 17891328ull   // + TB*16*TT
#define YATT_OFF 17895424ull   // + TB*TT
#define YSZ      3145728       // BTM*TC

typedef __attribute__((ext_vector_type(8))) short bf16x8;
typedef __attribute__((ext_vector_type(4))) float f32x4;

__device__ inline unsigned short f2bf(float f) {
    unsigned u = __float_as_uint(f);
    return (unsigned short)((u + 0x7fffu + ((u >> 16) & 1u)) >> 16);
}

// ------------------------------------------------------- fp32 -> bf16 cast
__global__ __launch_bounds__(256) void castbf(
    const float* __restrict__ in, unsigned short* __restrict__ out, int n8)
{
    int idx = blockIdx.x * 256 + threadIdx.x;
    if (idx >= n8) return;
    const float4* p = (const float4*)(in + (size_t)idx * 8);
    float4 a = p[0], b = p[1];
    union { unsigned short us[8]; uint4 u4; } r;
    r.us[0] = f2bf(a.x); r.us[1] = f2bf(a.y); r.us[2] = f2bf(a.z); r.us[3] = f2bf(a.w);
    r.us[4] = f2bf(b.x); r.us[5] = f2bf(b.y); r.us[6] = f2bf(b.z); r.us[7] = f2bf(b.w);
    *(uint4*)(out + (size_t)idx * 8) = r.u4;
}

// ------------------------------------- W[K][N] fp32 -> Wt[N][K] bf16 (64x64)
__global__ __launch_bounds__(256) void tcast(
    const float* __restrict__ W, unsigned short* __restrict__ Wt, int K, int N)
{
    __shared__ unsigned short T[64][80];   // row 160B, 16B-aligned rows
    const int tid = threadIdx.x;
    const int k0 = blockIdx.x * 64, n0 = blockIdx.y * 64;
#pragma unroll
    for (int u = 0; u < 4; ++u) {
        int f = u * 256 + tid;           // 0..1023
        int kr = f >> 4, nc = (f & 15) * 4;
        float4 v = *(const float4*)(W + (size_t)(k0 + kr) * N + n0 + nc);
        T[nc + 0][kr] = f2bf(v.x); T[nc + 1][kr] = f2bf(v.y);
        T[nc + 2][kr] = f2bf(v.z); T[nc + 3][kr] = f2bf(v.w);
    }
    __syncthreads();
#pragma unroll
    for (int u = 0; u < 2; ++u) {
        int f = u * 256 + tid;           // 0..511
        int nr = f >> 3, kc = (f & 7) * 8;
        *(uint4*)(Wt + (size_t)(n0 + nr) * K + k0 + kc) = *(uint4*)&T[nr][kc];
    }
}

// --------------------------------------------------------- bf16 MFMA GEMM
// C[M,N] = A[M,K] @ Bt[N,K]^T + bias[N]; fp32 out. 128x128 tile, BK=64,
// 4 waves, each wave a 64x64 quadrant of 4x4 MFMA 16x16x32_bf16 tiles.
__global__ __launch_bounds__(256) void gemm_bf16(
    const unsigned short* __restrict__ A, const unsigned short* __restrict__ Bt,
    const float* __restrict__ bias, float* __restrict__ C,
    int M, int N, int K)
{
    __shared__ unsigned short As[128 * 64];
    __shared__ unsigned short Bs[128 * 64];
    const int tid = threadIdx.x;
    const int w = tid >> 6, lane = tid & 63;
    const int row0 = blockIdx.y * 128, col0 = blockIdx.x * 128;
    const int moff = (w >> 1) * 64, noff = (w & 1) * 64;
    const int lm = lane & 15, quad = lane >> 4;

    f32x4 acc[4][4];
#pragma unroll
    for (int i = 0; i < 4; ++i)
#pragma unroll
        for (int j = 0; j < 4; ++j) acc[i][j] = (f32x4){0.f, 0.f, 0.f, 0.f};

    for (int k0 = 0; k0 < K; k0 += 64) {
        __syncthreads();
#pragma unroll
        for (int u = 0; u < 4; ++u) {
            int unit = u * 256 + tid;      // 0..1023
            int r = unit >> 3, kq = unit & 7;
            int kqs = kq ^ (r & 7);
            bf16x8 va = *(const bf16x8*)(A + (size_t)(row0 + r) * K + k0 + kq * 8);
            *(bf16x8*)&As[r * 64 + kqs * 8] = va;
            bf16x8 vb = *(const bf16x8*)(Bt + (size_t)(col0 + r) * K + k0 + kq * 8);
            *(bf16x8*)&Bs[r * 64 + kqs * 8] = vb;
        }
        __syncthreads();
#pragma unroll
        for (int kh = 0; kh < 2; ++kh) {
            const int kqb = kh * 4 + quad;
            bf16x8 af[4], bfr[4];
#pragma unroll
            for (int i = 0; i < 4; ++i) {
                int mr = moff + i * 16 + lm;
                af[i] = *(const bf16x8*)&As[mr * 64 + (kqb ^ (mr & 7)) * 8];
                int nr = noff + i * 16 + lm;
                bfr[i] = *(const bf16x8*)&Bs[nr * 64 + (kqb ^ (nr & 7)) * 8];
            }
#pragma unroll
            for (int i = 0; i < 4; ++i)
#pragma unroll
                for (int j = 0; j < 4; ++j)
                    acc[i][j] = __builtin_amdgcn_mfma_f32_16x16x32_bf16(
                        af[i], bfr[j], acc[i][j], 0, 0, 0);
        }
    }

#pragma unroll
    for (int j = 0; j < 4; ++j) {
        int n = col0 + noff + j * 16 + lm;
        float bv = bias[n];
#pragma unroll
        for (int i = 0; i < 4; ++i) {
            int mbase = row0 + moff + i * 16 + quad * 4;
#pragma unroll
            for (int r = 0; r < 4; ++r)
                C[(size_t)(mbase + r) * N + n] = acc[i][j][r] + bv;
        }
    }
}

// ------------------------------------------------- head-0 selection scores S
__global__ __launch_bounds__(256) void s_head0_kernel(
    const float* __restrict__ qkv, float* __restrict__ S)
{
    const int tid = threadIdx.x;
    const int tx = tid & 15, ty = tid >> 4;
    const int s0 = blockIdx.x * 64, t0 = blockIdx.y * 64, b = blockIdx.z;

    if (s0 > t0 + 63) {  // fully above diagonal: zero-fill
        float4 z = make_float4(0.f, 0.f, 0.f, 0.f);
#pragma unroll
        for (int i = 0; i < 4; ++i) {
            int t = t0 + ty * 4 + i;
            *(float4*)(S + ((size_t)b * TT + t) * TT + s0 + tx * 4) = z;
        }
        return;
    }

    __shared__ __align__(16) float As[16][68];
    __shared__ __align__(16) float Bs[16][68];
    float acc[4][4];
#pragma unroll
    for (int i = 0; i < 4; ++i)
#pragma unroll
        for (int j = 0; j < 4; ++j) acc[i][j] = 0.f;

    for (int k0 = 0; k0 < 64; k0 += 16) {
        int r = tid >> 2, c = (tid & 3) * 4;
        float4 av = *(const float4*)(qkv + ((size_t)b * TT + t0 + r) * QKVN + k0 + c);
        As[c + 0][r] = av.x; As[c + 1][r] = av.y;
        As[c + 2][r] = av.z; As[c + 3][r] = av.w;
        float4 bv = *(const float4*)(qkv + ((size_t)b * TT + s0 + r) * QKVN + 768 + k0 + c);
        Bs[c + 0][r] = bv.x; Bs[c + 1][r] = bv.y;
        Bs[c + 2][r] = bv.z; Bs[c + 3][r] = bv.w;
        __syncthreads();
#pragma unroll
        for (int kk = 0; kk < 16; ++kk) {
            float4 a4 = *(const float4*)&As[kk][ty * 4];
            float4 b4 = *(const float4*)&Bs[kk][tx * 4];
            float a[4] = {a4.x, a4.y, a4.z, a4.w};
            float bb[4] = {b4.x, b4.y, b4.z, b4.w};
#pragma unroll
            for (int i = 0; i < 4; ++i)
#pragma unroll
                for (int j = 0; j < 4; ++j)
                    acc[i][j] = fmaf(a[i], bb[j], acc[i][j]);
        }
        __syncthreads();
    }

#pragma unroll
    for (int i = 0; i < 4; ++i) {
        int t = t0 + ty * 4 + i;
        int sb = s0 + tx * 4;
        float4 o;
        o.x = (sb + 0 > 0 && sb + 0 < t) ? fmaxf(acc[i][0] * 0.125f, 0.f) : 0.f;
        o.y = (sb + 1 > 0 && sb + 1 < t) ? fmaxf(acc[i][1] * 0.125f, 0.f) : 0.f;
        o.z = (sb + 2 > 0 && sb + 2 < t) ? fmaxf(acc[i][2] * 0.125f, 0.f) : 0.f;
        o.w = (sb + 3 > 0 && sb + 3 < t) ? fmaxf(acc[i][3] * 0.125f, 0.f) : 0.f;
        *(float4*)(S + ((size_t)b * TT + t) * TT + sb) = o;
    }
}

// ---------------------------------------------- segmented exclusive scan (t)
__global__ void scan_pass1(const float* __restrict__ S, float* __restrict__ gsum)
{
    int s = blockIdx.x * 256 + threadIdx.x;
    int g = blockIdx.y, b = blockIdx.z;
    const float* base = S + ((size_t)b * TT + g * 128) * TT + s;
    float acc = 0.f;
#pragma unroll 4
    for (int r = 0; r < 128; ++r) acc += base[(size_t)r * TT];
    gsum[((size_t)b * 16 + g) * TT + s] = acc;
}

__global__ void scan_pass2(float* __restrict__ gsum)
{
    int idx = blockIdx.x * 256 + threadIdx.x;  // 0..4095
    int b = idx >> 11, s = idx & 2047;
    float acc = 0.f;
#pragma unroll
    for (int g = 0; g < 16; ++g) {
        size_t a = ((size_t)b * 16 + g) * TT + s;
        float v = gsum[a];
        gsum[a] = acc;
        acc += v;
    }
}

__global__ void scan_pass3(float* __restrict__ S, const float* __restrict__ gsum)
{
    int s = blockIdx.x * 256 + threadIdx.x;
    int g = blockIdx.y, b = blockIdx.z;
    float acc = gsum[((size_t)b * 16 + g) * TT + s];
    float* base = S + ((size_t)b * TT + g * 128) * TT + s;
#pragma unroll 4
    for (int r = 0; r < 128; ++r) {
        float v = base[(size_t)r * TT];
        base[(size_t)r * TT] = acc;
        acc += v;
    }
}

// ------------------------------------------------- FF_sum[b,t] = sum clip(FF)
__global__ void ffsum_kernel(const float* __restrict__ FF, float* __restrict__ FS)
{
    int row = blockIdx.x;  // b*TT + t
    int tid = threadIdx.x;
    const float* p = FF + (size_t)row * TT;
    float acc = 0.f;
#pragma unroll
    for (int s = tid; s < TT; s += 256) {
        float v = p[s];
        acc += fminf(fmaxf(v, 0.f), 1.f);
    }
#pragma unroll
    for (int off = 32; off > 0; off >>= 1) acc += __shfl_down(acc, off, 64);
    __shared__ float red[4];
    if ((tid & 63) == 0) red[tid >> 6] = acc;
    __syncthreads();
    if (tid == 0) FS[row] = (red[0] + red[1]) + (red[2] + red[3]);
}

// ----------------------------------------------------- M[0,b,i,j] = i - FS[b,j]
__global__ void mout_kernel(const float* __restrict__ FS, float* __restrict__ Mo)
{
    size_t idx = (size_t)blockIdx.x * 256 + threadIdx.x;
    int j = (int)(idx & 2047);
    int i = (int)((idx >> 11) & 2047);
    int b = (int)(idx >> 22);
    Mo[idx] = (float)i - FS[b * TT + j];
}

// -------------------------------------------- flash attention, bf16 MFMA
// v4: per (b,h,64-q-rows) block, 4 waves. Computes S^T = mfma(K-frag, Q-frag)
// so Q fragments live in registers and softmax reduces with 2 shfl_xor across
// quads. P^T round-trips LDS (2-way conflict writes) into A-layout; V is
// transposed into [d][s] during staging. O accumulates in C-layout; bf16 out.
__global__ __launch_bounds__(256) void attn_kernel(
    const float* __restrict__ qkv, const float* __restrict__ FF,
    unsigned short* __restrict__ Yb)
{
    const int sblk = blockIdx.x;           // 0..767
    const int hi = sblk >> 5;              // 0..23
    const int tt = (sblk ^ hi) & 31;       // bijective fold per 32-group
    const int h = hi % NHD;
    const int b = hi / NHD;

    const int tid = threadIdx.x;
    const int w = tid >> 6, lane = tid & 63;
    const int lm = lane & 15, quad = lane >> 4;
    const int t0 = tt * 64;

    __shared__ unsigned short Ks[64 * 64];   // K: [s][d], XOR-swizzled d-groups
    __shared__ unsigned short Vt[64 * 64];   // V^T: [d][s], XOR-swizzled s-groups
    __shared__ unsigned short Ps[64 * 64];   // P: [q][s], XOR-swizzled s-groups

    // ---- Q B-fragments in registers (n = q = w*16+lm, k = kh*32+quad*8+j) ----
    const int tq = t0 + w * 16 + lm;
    bf16x8 qf[2];
#pragma unroll
    for (int kh = 0; kh < 2; ++kh) {
        const float* qp = qkv + ((size_t)(b * TT) + tq) * QKVN + h * 64 + kh * 32 + quad * 8;
        float4 a = *(const float4*)qp;
        float4 c = *(const float4*)(qp + 4);
        union { unsigned short us[8]; bf16x8 v; } u;
        u.us[0] = f2bf(a.x); u.us[1] = f2bf(a.y); u.us[2] = f2bf(a.z); u.us[3] = f2bf(a.w);
        u.us[4] = f2bf(c.x); u.us[5] = f2bf(c.y); u.us[6] = f2bf(c.z); u.us[7] = f2bf(c.w);
        qf[kh] = u.v;
    }

    f32x4 accO[4];
#pragma unroll
    for (int j = 0; j < 4; ++j) accO[j] = (f32x4){0.f, 0.f, 0.f, 0.f};
    float m_c = -3.0e38f, l_c = 0.f;

#pragma unroll 1
    for (int it = 0; it <= tt; ++it) {
        const int s0 = it * 64;
        __syncthreads();   // all waves done with prior Ks/Vt reads

        // ---- stage K [s][d] bf16 swizzled ----
#pragma unroll
        for (int u = 0; u < 2; ++u) {
            int unit = u * 256 + tid;   // 0..511
            int r = unit >> 3, kq = unit & 7;
            const float* kp = qkv + ((size_t)(b * TT) + s0 + r) * QKVN + 768 + h * 64 + kq * 8;
            float4 a = *(const float4*)kp;
            float4 c = *(const float4*)(kp + 4);
            union { unsigned short us[8]; bf16x8 v; } uu;
            uu.us[0] = f2bf(a.x); uu.us[1] = f2bf(a.y); uu.us[2] = f2bf(a.z); uu.us[3] = f2bf(a.w);
            uu.us[4] = f2bf(c.x); uu.us[5] = f2bf(c.y); uu.us[6] = f2bf(c.z); uu.us[7] = f2bf(c.w);
            *(bf16x8*)&Ks[r * 64 + (kq ^ (r & 7)) * 8] = uu.v;
        }
        // ---- stage V^T [d][s]: wave w covers d = w*16..w*16+15, s = lane ----
        {
            int s = lane;
            const float* vp = qkv + ((size_t)(b * TT) + s0 + s) * QKVN + 1536 + h * 64 + w * 16;
            float4 v0 = *(const float4*)(vp + 0);
            float4 v1 = *(const float4*)(vp + 4);
            float4 v2 = *(const float4*)(vp + 8);
            float4 v3 = *(const float4*)(vp + 12);
            float vv[16] = {v0.x, v0.y, v0.z, v0.w, v1.x, v1.y, v1.z, v1.w,
                            v2.x, v2.y, v2.z, v2.w, v3.x, v3.y, v3.z, v3.w};
            const int sg = s >> 3, sl = s & 7;
#pragma unroll
            for (int dd = 0; dd < 16; ++dd) {
                int d = w * 16 + dd;
                Vt[d * 64 + (sg ^ (d & 7)) * 8 + sl] = f2bf(vv[dd]);
            }
        }
        __syncthreads();

        // ---- S^T = K Q^T: D[m=s][n=q], 4 m-tiles x 2 k-halves per wave ----
        f32x4 accS[4];
#pragma unroll
        for (int mi = 0; mi < 4; ++mi) accS[mi] = (f32x4){0.f, 0.f, 0.f, 0.f};
#pragma unroll
        for (int kh = 0; kh < 2; ++kh)
#pragma unroll
            for (int mi = 0; mi < 4; ++mi) {
                int sr = mi * 16 + lm;
                bf16x8 kf = *(const bf16x8*)&Ks[sr * 64 + ((kh * 4 + quad) ^ (sr & 7)) * 8];
                accS[mi] = __builtin_amdgcn_mfma_f32_16x16x32_bf16(kf, qf[kh], accS[mi], 0, 0, 0);
            }

        // ---- logits + online softmax (lane holds col q=tq, rows s) ----
        float sc[4][4];
        float rm = -3.0e38f;
        const float* ffrow = FF + ((size_t)(b * TT) + tq) * TT + s0;
#pragma unroll
        for (int mi = 0; mi < 4; ++mi) {
            float4 f4 = *(const float4*)(ffrow + mi * 16 + quad * 4);
            float fa[4] = {f4.x, f4.y, f4.z, f4.w};
#pragma unroll
            for (int r = 0; r < 4; ++r) {
                float v = accS[mi][r] * 0.125f - fa[r];
                if (it == tt && s0 + mi * 16 + quad * 4 + r > tq) v = -3.0e38f;
                sc[mi][r] = v;
                rm = fmaxf(rm, v);
            }
        }
        rm = fmaxf(rm, __shfl_xor(rm, 16, 64));
        rm = fmaxf(rm, __shfl_xor(rm, 32, 64));
        float mnew = fmaxf(m_c, rm);
        float alpha = __expf(m_c - mnew);
        m_c = mnew;
        float rs = 0.f;
#pragma unroll
        for (int mi = 0; mi < 4; ++mi)
#pragma unroll
            for (int r = 0; r < 4; ++r) {
                float p = __expf(sc[mi][r] - mnew);
                sc[mi][r] = p;
                rs += p;
            }
        rs += __shfl_xor(rs, 16, 64);
        rs += __shfl_xor(rs, 32, 64);
        l_c = l_c * alpha + rs;

        // ---- rescale O (rows q = quad*4+r need alpha from col-lane q) ----
        float a_r[4];
#pragma unroll
        for (int r = 0; r < 4; ++r) a_r[r] = __shfl(alpha, quad * 4 + r, 64);
#pragma unroll
        for (int nj = 0; nj < 4; ++nj)
#pragma unroll
            for (int r = 0; r < 4; ++r) accO[nj][r] *= a_r[r];

        // ---- store P[q][s] bf16 (own rows only: in-wave LDS dependency) ----
        const int qrow = w * 16 + lm;
#pragma unroll
        for (int mi = 0; mi < 4; ++mi)
#pragma unroll
            for (int r = 0; r < 4; ++r) {
                int sr = mi * 16 + quad * 4 + r;
                Ps[qrow * 64 + ((sr >> 3) ^ (qrow & 7)) * 8 + (sr & 7)] = f2bf(sc[mi][r]);
            }

        // ---- O += P V: D[m=q][n=d] = mfma(P-frag, V^T-frag) ----
        bf16x8 pf[2];
#pragma unroll
        for (int kh = 0; kh < 2; ++kh)
            pf[kh] = *(const bf16x8*)&Ps[qrow * 64 + ((kh * 4 + quad) ^ (qrow & 7)) * 8];
#pragma unroll
        for (int kh = 0; kh < 2; ++kh)
#pragma unroll
            for (int nj = 0; nj < 4; ++nj) {
                int dr = nj * 16 + lm;
                bf16x8 vf = *(const bf16x8*)&Vt[dr * 64 + ((kh * 4 + quad) ^ (dr & 7)) * 8];
                accO[nj] = __builtin_amdgcn_mfma_f32_16x16x32_bf16(pf[kh], vf, accO[nj], 0, 0, 0);
            }
    }

    // ---- epilogue: normalize rows, write bf16 ----
    float l_r[4];
#pragma unroll
    for (int r = 0; r < 4; ++r) l_r[r] = __shfl(l_c, quad * 4 + r, 64);
#pragma unroll
    for (int nj = 0; nj < 4; ++nj)
#pragma unroll
        for (int r = 0; r < 4; ++r) {
            int trow = t0 + w * 16 + quad * 4 + r;
            Yb[((size_t)(b * TT) + trow) * TC + h * 64 + nj * 16 + lm] =
                f2bf(accO[nj][r] / l_r[r]);
        }
}

// ---------------------------------------------------------------------- launch
extern "C" void kernel_launch(void* const* d_in, const int* in_sizes, int n_in,
                              void* d_out, int out_size, void* d_ws, size_t ws_size,
                              hipStream_t stream)
{
    const float* x      = (const float*)d_in[0];
    const float* W_attn = (const float*)d_in[1];
    const float* b_attn = (const float*)d_in[2];
    const float* W_proj = (const float*)d_in[3];
    const float* b_proj = (const float*)d_in[4];
    float* out = (float*)d_out;
    float* ws  = (float*)d_ws;

    float* qkv  = ws;                 // [4096, 2304] fp32
    float* FFb  = ws + FF_OFF;        // [B, T, T]   S -> FF in place
    float* gsum = ws + GSUM_OFF;      // [B, 16, T]
    float* fsum = ws + FSUM_OFF;      // [B, T]

    // bf16 aliases (live ranges disjoint):
    //   FF region before s_head0: xb [4096*768], WtA [2304*768]
    //   FF region after attn:     WtP [768*768]
    //   yatt region:              ytb [4096*768] bf16 (attn output)
    unsigned short* xb  = (unsigned short*)(ws + FF_OFF);
    unsigned short* WtA = xb + (size_t)BTM * TC;
    unsigned short* WtP = (unsigned short*)(ws + FF_OFF);
    unsigned short* ytb = (unsigned short*)(ws + YATT_OFF);

    castbf<<<dim3(1536), dim3(256), 0, stream>>>(x, xb, BTM * TC / 8);
    tcast<<<dim3(TC / 64, QKVN / 64), dim3(256), 0, stream>>>(W_attn, WtA, TC, QKVN);

    gemm_bf16<<<dim3(QKVN / 128, BTM / 128), dim3(256), 0, stream>>>(
        xb, WtA, b_attn, qkv, BTM, QKVN, TC);

    s_head0_kernel<<<dim3(TT / 64, TT / 64, TB), dim3(256), 0, stream>>>(qkv, FFb);

    scan_pass1<<<dim3(TT / 256, 16, TB), dim3(256), 0, stream>>>(FFb, gsum);
    scan_pass2<<<dim3(TB * TT / 256), dim3(256), 0, stream>>>(gsum);
    scan_pass3<<<dim3(TT / 256, 16, TB), dim3(256), 0, stream>>>(FFb, gsum);

    ffsum_kernel<<<dim3(TB * TT), dim3(256), 0, stream>>>(FFb, fsum);

    attn_kernel<<<dim3(TT / 64 * NHD * TB), dim3(256), 0, stream>>>(qkv, FFb, ytb);

    tcast<<<dim3(TC / 64, TC / 64), dim3(256), 0, stream>>>(W_proj, WtP, TC, TC);

    gemm_bf16<<<dim3(TC / 128, BTM / 128), dim3(256), 0, stream>>>(
        ytb, WtP, b_proj, out, BTM, TC, TC);

    mout_kernel<<<dim3((unsigned)((size_t)TB * TT * TT / 256)), dim3(256), 0, stream>>>(
        fsum, out + YSZ);
}